// Round 13
// baseline (78.206 us; speedup 1.0000x reference)
//
#include <hip/hip_runtime.h>
#include <hip/hip_bf16.h>
#include <math.h>

#define S_LEN 2048
#define H_DIM 1024
#define NHEAD 16
#define HD 64
#define NMEM 4
#define NCHUNK 32
#define CLEN 64
#define EPS_C 1e-6f

typedef __attribute__((ext_vector_type(8))) short bf16x8;
typedef __attribute__((ext_vector_type(4))) float f32x4;
typedef __attribute__((ext_vector_type(8))) unsigned short u16x8;
typedef __attribute__((ext_vector_type(4))) unsigned short u16x4;

__device__ __forceinline__ unsigned short f2bf(float f) {
    unsigned int u = __float_as_uint(f);
    u += 0x7FFFu + ((u >> 16) & 1u);   // round-to-nearest-even
    return (unsigned short)(u >> 16);
}
__device__ __forceinline__ float bf2f(unsigned short u) {
    return __uint_as_float((unsigned int)u << 16);
}

// swizzle for 64-col bf16 tiles, 128B rows (G4: byte ^= (row&7)<<4)
#define SWZ(row, colbyte) ((row) * 128 + ((colbyte) ^ (((row) & 7) << 4)))

// ---------------------------------------------------------------------------
// prep: all f32->bf16 conversions + memories transpose, one launch.
// ---------------------------------------------------------------------------
__global__ __launch_bounds__(256) void prep_kernel(const float* __restrict__ hidden,
                                                   const float* __restrict__ w_q,
                                                   const float* __restrict__ w_k,
                                                   const float* __restrict__ w_v,
                                                   const float* __restrict__ w_o,
                                                   const float* __restrict__ memories,
                                                   unsigned short* __restrict__ hb,
                                                   unsigned short* __restrict__ wb,
                                                   unsigned short* __restrict__ wob,
                                                   unsigned short* __restrict__ mbT) {
    const int b = blockIdx.x;
    const int tid = threadIdx.x;
    __shared__ float t[64][65];
    if (b < 3072) {
        const float* src;
        unsigned short* dst;
        int base;
        if (b < 1024)      { src = hidden; dst = hb;            base = b; }
        else if (b < 1536) { src = w_q;    dst = wb;            base = b - 1024; }
        else if (b < 2048) { src = w_k;    dst = wb + 1048576;  base = b - 1536; }
        else if (b < 2560) { src = w_v;    dst = wb + 2097152;  base = b - 2048; }
        else               { src = w_o;    dst = wob;           base = b - 2560; }
        const int i = base * 2048 + tid * 8;
        float4 a = *(const float4*)(src + i);
        float4 c = *(const float4*)(src + i + 4);
        u16x8 o;
        o[0] = f2bf(a.x); o[1] = f2bf(a.y); o[2] = f2bf(a.z); o[3] = f2bf(a.w);
        o[4] = f2bf(c.x); o[5] = f2bf(c.y); o[6] = f2bf(c.z); o[7] = f2bf(c.w);
        *(u16x8*)(dst + i) = o;
    } else {
        const int mh = b - 3072;
        const float* src = memories + (size_t)mh * 4096;
#pragma unroll
        for (int j = 0; j < 4; ++j) {
            const int idx = j * 1024 + tid * 4;
            *(float4*)&t[idx >> 6][idx & 63] = *(const float4*)&src[idx];
        }
        __syncthreads();
        unsigned short* dst = mbT + (size_t)mh * 4096;
#pragma unroll
        for (int j = 0; j < 4; ++j) {
            const int idx = j * 1024 + tid * 4;
            const int e = idx >> 6, d = idx & 63;
            u16x4 o;
#pragma unroll
            for (int i = 0; i < 4; ++i) o[i] = f2bf(t[d + i][e]);
            *(u16x4*)&dst[idx] = o;
        }
    }
}

// ---------------------------------------------------------------------------
// MFMA bf16 GEMM, BM=64 x BN(template), BK=64 (two 32-planes), double-buffered
// LDS, prefetch-before-compute (one barrier per K-tile). XCD-chunked 1D grid.
// MODE 0: f32 out (no act). MODE 1 (BN=128): qkv, bf16 out, elu1 on seg 0/1.
// ---------------------------------------------------------------------------
template <int MODE, int BN>
__global__ __launch_bounds__(256) void gemm_mfma_kernel(const unsigned short* __restrict__ A,
                                                        const unsigned short* __restrict__ B,
                                                        float* __restrict__ f32out,
                                                        unsigned short* __restrict__ b0,
                                                        unsigned short* __restrict__ b1,
                                                        unsigned short* __restrict__ b2,
                                                        int K, int perx) {
    constexpr int NNI = BN / 32;        // B col-frags per wave
    __shared__ unsigned short Als[2][2][64][32];    // buf, kplane, row, k
    __shared__ unsigned short Bls[2][2][BN][32];
    const int tid  = threadIdx.x;
    const int lane = tid & 63;
    const int wv   = tid >> 6;
    const int wr   = wv >> 1;
    const int wc   = wv & 1;
    const int d    = blockIdx.x;
    const int xcd  = d & 7;
    const int j    = d >> 3;
    const int y    = xcd * perx + (j >> 5);
    const int x    = j & 31;
    const int bm   = x * 64;
    const int bn   = y * BN;

    const int lrow = lane >> 2;
    const int skc  = (lane & 3) << 3;
    const unsigned short* gA = A + (size_t)(bm + (wv << 4) + lrow) * K + skc;
    const unsigned short* gB = B + (size_t)(bn + wv * (BN / 4) + lrow) * K + skc;

    const int frow = lane & 15;
    const int fkof = (lane >> 4) << 3;

    f32x4 acc[2][NNI] = {};

    auto stage = [&](int buf, int t) {
        const size_t ko = (size_t)t * 64;
#pragma unroll
        for (int pl = 0; pl < 2; ++pl) {
            __builtin_amdgcn_global_load_lds(
                (const __attribute__((address_space(1))) void*)(gA + ko + pl * 32),
                (__attribute__((address_space(3))) void*)&Als[buf][pl][wv << 4][0], 16, 0, 0);
#pragma unroll
            for (int q = 0; q < BN / 64; ++q)
                __builtin_amdgcn_global_load_lds(
                    (const __attribute__((address_space(1))) void*)(gB + (size_t)q * 16 * K + ko + pl * 32),
                    (__attribute__((address_space(3))) void*)&Bls[buf][pl][wv * (BN / 4) + q * 16][0], 16, 0, 0);
        }
    };

    const int NT = K >> 6;   // 16 for K=1024
    stage(0, 0);
    __syncthreads();
    int cur = 0;
    for (int t = 0; t < NT; ++t) {
        if (t + 1 < NT) stage(cur ^ 1, t + 1);   // prefetch next tile (overlaps compute)
        bf16x8 af[2][2], bf[2][NNI];
#pragma unroll
        for (int pl = 0; pl < 2; ++pl) {
#pragma unroll
            for (int mi = 0; mi < 2; ++mi)
                af[pl][mi] = *(const bf16x8*)&Als[cur][pl][wr * 32 + mi * 16 + frow][fkof];
#pragma unroll
            for (int ni = 0; ni < NNI; ++ni)
                bf[pl][ni] = *(const bf16x8*)&Bls[cur][pl][wc * (BN / 2) + ni * 16 + frow][fkof];
        }
#pragma unroll
        for (int pl = 0; pl < 2; ++pl)
#pragma unroll
            for (int mi = 0; mi < 2; ++mi)
#pragma unroll
                for (int ni = 0; ni < NNI; ++ni)
                    acc[mi][ni] = __builtin_amdgcn_mfma_f32_16x16x32_bf16(af[pl][mi], bf[pl][ni], acc[mi][ni], 0, 0, 0);
        __syncthreads();   // drains prefetch vmcnt + protects buf reuse
        cur ^= 1;
    }

    unsigned short* bdst = b0;
    int colbase = bn;
    bool act = false;
    if (MODE == 1) {
        const int seg = bn >> 10;
        bdst = (seg == 0) ? b0 : ((seg == 1) ? b1 : b2);
        colbase = bn & 1023;
        act = (seg < 2);
    }
    const int crow = (lane >> 4) << 2;
    const int ccol = lane & 15;
#pragma unroll
    for (int mi = 0; mi < 2; ++mi) {
#pragma unroll
        for (int ni = 0; ni < NNI; ++ni) {
            const int col = colbase + wc * (BN / 2) + ni * 16 + ccol;
#pragma unroll
            for (int r = 0; r < 4; ++r) {
                const int row = bm + wr * 32 + mi * 16 + crow + r;
                float xv = acc[mi][ni][r];
                if (MODE == 0) {
                    f32out[(size_t)row * 1024 + col] = xv;
                } else {
                    if (act) xv = (xv > 0.f) ? (xv + 1.f) : __expf(xv);
                    bdst[(size_t)row * 1024 + col] = f2bf(xv);
                }
            }
        }
    }
}

// ---------------------------------------------------------------------------
// chunkkv + rel merged kernel. grid (NHEAD, 36):
//   y <  32: chunkkv for chunk y  -> ckv_b (bf16), cksc
//   y >= 32: rel for s-segment (y-32)*512 -> rel, relpart
// ---------------------------------------------------------------------------
__global__ __launch_bounds__(256) void chunkkv_rel_kernel(const unsigned short* __restrict__ kb,
                                                          const unsigned short* __restrict__ vb,
                                                          const unsigned short* __restrict__ qb,
                                                          const float* __restrict__ norms,
                                                          unsigned short* __restrict__ ckv_b,
                                                          float* __restrict__ cksc,
                                                          float* __restrict__ rel,
                                                          float* __restrict__ relpart) {
    const int h = blockIdx.x;
    const int tid = threadIdx.x;
    __shared__ unsigned short KT[4096], VT[4096];
    __shared__ float red[256];

    if (blockIdx.y >= 32) {
        // ---------------- rel path ----------------
        const int seg = blockIdx.y - 32;
        float* nl = (float*)KT;          // reuse LDS: 4*64 floats
        {
            const int m = tid >> 6, dd = tid & 63;
            nl[m * 64 + dd] = norms[(size_t)(m * NHEAD + h) * HD + dd];
        }
        __syncthreads();
        float sums[4] = {0.f, 0.f, 0.f, 0.f};
#pragma unroll
        for (int it = 0; it < 2; ++it) {
            const int s = seg * 512 + it * 256 + tid;
            const unsigned short* row = qb + (size_t)s * H_DIM + h * HD;
            float dot[4] = {0.f, 0.f, 0.f, 0.f};
#pragma unroll
            for (int d0 = 0; d0 < 64; d0 += 8) {
                u16x8 v = *(const u16x8*)(row + d0);
#pragma unroll
                for (int i = 0; i < 8; ++i) {
                    const float qv = bf2f(v[i]);
                    dot[0] = fmaf(qv, nl[0 * 64 + d0 + i], dot[0]);
                    dot[1] = fmaf(qv, nl[1 * 64 + d0 + i], dot[1]);
                    dot[2] = fmaf(qv, nl[2 * 64 + d0 + i], dot[2]);
                    dot[3] = fmaf(qv, nl[3 * 64 + d0 + i], dot[3]);
                }
            }
#pragma unroll
            for (int m = 0; m < NMEM; ++m) {
                rel[(size_t)(m * NHEAD + h) * S_LEN + s] = dot[m];
                sums[m] += dot[m];
            }
        }
#pragma unroll
        for (int m = 0; m < NMEM; ++m) {
            red[tid] = sums[m];
            __syncthreads();
            for (int o = 128; o > 0; o >>= 1) {
                if (tid < o) red[tid] += red[tid + o];
                __syncthreads();
            }
            if (tid == 0) relpart[(m * NHEAD + h) * 4 + seg] = red[0];
            __syncthreads();
        }
        return;
    }

    // ---------------- chunkkv path ----------------
    const int c = blockIdx.y;
    const int s0 = c * CLEN;
    char* KTb = (char*)KT;
    char* VTb = (char*)VT;
    const int lane = tid & 63;
    const int w = tid >> 6;
    const int fr = lane & 15;
    const int fk = (lane >> 4) * 8;
    const int er = w * 16 + (lane >> 4) * 4;

    const int idx0 = tid * 8, idx1 = 2048 + tid * 8;
    const int r0 = idx0 >> 6, c0 = idx0 & 63;
    const int r1 = idx1 >> 6, c1 = idx1 & 63;

    u16x8 k0 = *(const u16x8*)&kb[(size_t)(s0 + r0) * H_DIM + h * HD + c0];
    u16x8 k1 = *(const u16x8*)&kb[(size_t)(s0 + r1) * H_DIM + h * HD + c1];
    u16x8 v0 = *(const u16x8*)&vb[(size_t)(s0 + r0) * H_DIM + h * HD + c0];
    u16x8 v1 = *(const u16x8*)&vb[(size_t)(s0 + r1) * H_DIM + h * HD + c1];
#pragma unroll
    for (int j = 0; j < 8; ++j) {
        *(unsigned short*)(KTb + SWZ(c0 + j, r0 * 2)) = (unsigned short)k0[j];
        *(unsigned short*)(KTb + SWZ(c1 + j, r1 * 2)) = (unsigned short)k1[j];
        *(unsigned short*)(VTb + SWZ(c0 + j, r0 * 2)) = (unsigned short)v0[j];
        *(unsigned short*)(VTb + SWZ(c1 + j, r1 * 2)) = (unsigned short)v1[j];
    }
    __syncthreads();

    bf16x8 a0 = *(bf16x8*)(VTb + SWZ(w * 16 + fr, fk * 2));
    bf16x8 a1 = *(bf16x8*)(VTb + SWZ(w * 16 + fr, (32 + fk) * 2));
    f32x4 acc[4] = {};
    bf16x8 ones;
#pragma unroll
    for (int i = 0; i < 8; ++i) ones[i] = (short)0x3F80;
    bf16x8 bw0 = *(bf16x8*)(KTb + SWZ(w * 16 + fr, fk * 2));
    bf16x8 bw1 = *(bf16x8*)(KTb + SWZ(w * 16 + fr, (32 + fk) * 2));
    f32x4 ka = {};
    ka = __builtin_amdgcn_mfma_f32_16x16x32_bf16(ones, bw0, ka, 0, 0, 0);
    ka = __builtin_amdgcn_mfma_f32_16x16x32_bf16(ones, bw1, ka, 0, 0, 0);
#pragma unroll
    for (int nt = 0; nt < 4; ++nt) {
        bf16x8 b0 = *(bf16x8*)(KTb + SWZ(nt * 16 + fr, fk * 2));
        bf16x8 b1 = *(bf16x8*)(KTb + SWZ(nt * 16 + fr, (32 + fk) * 2));
        acc[nt] = __builtin_amdgcn_mfma_f32_16x16x32_bf16(a0, b0, acc[nt], 0, 0, 0);
        acc[nt] = __builtin_amdgcn_mfma_f32_16x16x32_bf16(a1, b1, acc[nt], 0, 0, 0);
    }

    unsigned short* dst = ckv_b + ((size_t)(h * NCHUNK + c) << 12);
#pragma unroll
    for (int nt = 0; nt < 4; ++nt) {
        const int dd = nt * 16 + fr;
#pragma unroll
        for (int r = 0; r < 4; ++r)
            dst[(er + r) * 64 + dd] = f2bf(acc[nt][r]);
    }
    if (lane < 16)
        cksc[(size_t)(h * NCHUNK + c) * HD + w * 16 + lane] = ka[0];
}

// ---------------------------------------------------------------------------
// prefix: exclusive scan over chunks. All 32 chunk values loaded upfront.
// ---------------------------------------------------------------------------
__global__ __launch_bounds__(256) void prefix_kernel(const unsigned short* __restrict__ ckv_b,
                                                     const float* __restrict__ cksc,
                                                     unsigned short* __restrict__ ckvT_b,
                                                     float* __restrict__ cks) {
    const int h = blockIdx.x;
    const int g = blockIdx.y;
    const int tid = threadIdx.x;
    const int fo = g * 512 + tid * 2;
    const size_t base = ((size_t)(h * NCHUNK)) << 12;
    unsigned int vals[NCHUNK];
#pragma unroll
    for (int c = 0; c < NCHUNK; ++c)
        vals[c] = *(const unsigned int*)&ckv_b[base + ((size_t)c << 12) + fo];
    float rx = 0.f, ry = 0.f;
#pragma unroll
    for (int c = 0; c < NCHUNK; ++c) {
        *(unsigned int*)&ckvT_b[base + ((size_t)c << 12) + fo] =
            ((unsigned int)f2bf(ry) << 16) | (unsigned int)f2bf(rx);
        rx += bf2f((unsigned short)(vals[c] & 0xFFFF));
        ry += bf2f((unsigned short)(vals[c] >> 16));
    }
    if (g == 0 && tid < 64) {
        float kv[NCHUNK];
#pragma unroll
        for (int c = 0; c < NCHUNK; ++c)
            kv[c] = cksc[(size_t)(h * NCHUNK + c) * HD + tid];
        float rk = 0.f;
#pragma unroll
        for (int c = 0; c < NCHUNK; ++c) {
            cks[(size_t)(h * NCHUNK + c) * HD + tid] = rk;
            rk += kv[c];
        }
    }
}

// ---------------------------------------------------------------------------
// Fused output kernel, 32-row tiles: grid (NHEAD, 64); block = (h, half-chunk).
// c = y>>1, half = y&1. Q rows [s0, s0+32), K/V rows [c*64, c*64+64).
// LDS ~34KB -> 4 blocks/CU. Wave w: s-tile (w>>1), t/e-half (w&1).
// ---------------------------------------------------------------------------
__global__ __launch_bounds__(256) void fused_out_kernel(const unsigned short* __restrict__ qb,
                                                        const unsigned short* __restrict__ kb,
                                                        const unsigned short* __restrict__ vb,
                                                        const unsigned short* __restrict__ ckvT_b,
                                                        const float* __restrict__ cks,
                                                        const unsigned short* __restrict__ mbT,
                                                        const float* __restrict__ rel,
                                                        const float* __restrict__ relpart,
                                                        const float* __restrict__ gate,
                                                        unsigned short* __restrict__ cb) {
    const int h = blockIdx.x;
    const int hc = blockIdx.y;
    const int c = hc >> 1;
    const int half = hc & 1;
    const int s0 = c * CLEN + half * 32;   // Q-row base (global)
    const int kb0 = c * CLEN;              // K/V-row base (global)
    __shared__ unsigned short Qs[2048], Ks[4096], VsT[4096], KVsT[4096], Ps[2048];
    __shared__ float kp_lds[64];
    __shared__ float den_qkp[32];
    __shared__ float den_qk[2][32];
    __shared__ float c_lds[4][32];
    char* Qb  = (char*)Qs;
    char* Kb  = (char*)Ks;
    char* Vb  = (char*)VsT;
    char* KVb = (char*)KVsT;
    char* Pb  = (char*)Ps;
    const int tid = threadIdx.x;
    const int lane = tid & 63;
    const int w = tid >> 6;

    // --- stage Q (32x64) ---
    {
        const int idx = tid * 8;
        const int r = idx >> 6, cc = idx & 63;
        u16x8 q8 = *(const u16x8*)&qb[(size_t)(s0 + r) * H_DIM + h * HD + cc];
        *(u16x8*)(Qb + SWZ(r, cc * 2)) = q8;
    }
    // --- stage K (row-major), V (transposed), KVpre^T (64x64 each) ---
    const unsigned short* kvsrc = ckvT_b + ((size_t)(h * NCHUNK + c) << 12);
#pragma unroll
    for (int p = 0; p < 2; ++p) {
        const int idx = p * 2048 + tid * 8;
        const int r = idx >> 6, cc = idx & 63;
        const size_t gidx = (size_t)(kb0 + r) * H_DIM + h * HD + cc;
        u16x8 k8 = *(const u16x8*)&kb[gidx];
        u16x8 v8 = *(const u16x8*)&vb[gidx];
        *(u16x8*)(Kb + SWZ(r, cc * 2)) = k8;
#pragma unroll
        for (int j = 0; j < 8; ++j)
            *(unsigned short*)(Vb + SWZ(cc + j, r * 2)) = (unsigned short)v8[j];
        *(u16x8*)(KVb + SWZ(r, cc * 2)) = *(const u16x8*)&kvsrc[idx];
    }
    if (tid < 64) kp_lds[tid] = cks[(size_t)(h * NCHUNK + c) * HD + tid];
    if (tid >= 128 && tid < 256) {
        // inline softmax weights over memories (from 4-segment partials)
        const int m = (tid - 128) >> 5, si = tid & 31;
        float v[NMEM], mx = -1e30f;
#pragma unroll
        for (int mm = 0; mm < NMEM; ++mm) {
            const float* rp = &relpart[(mm * NHEAD + h) * 4];
            v[mm] = (rp[0] + rp[1] + rp[2] + rp[3]) * (1.f / (float)S_LEN);
            mx = fmaxf(mx, v[mm]);
        }
        float sum = 0.f;
#pragma unroll
        for (int mm = 0; mm < NMEM; ++mm) { v[mm] = __expf(v[mm] - mx); sum += v[mm]; }
        const float wgt = v[m] / sum;
        c_lds[m][si] = wgt / fmaxf(rel[(size_t)(m * NHEAD + h) * S_LEN + s0 + si], EPS_C);
    }
    __syncthreads();

    // --- den_qkp[s] = q[s]·kpre (rows 0..31; threads 0..127) ---
    if (tid < 128) {
        const int s = tid >> 2, part = tid & 3;
        bf16x8 q0 = *(bf16x8*)(Qb + SWZ(s, (part * 16) * 2));
        bf16x8 q1 = *(bf16x8*)(Qb + SWZ(s, (part * 16 + 8) * 2));
        float acc = 0.f;
#pragma unroll
        for (int jj = 0; jj < 8; ++jj) {
            acc = fmaf(bf2f((unsigned short)q0[jj]), kp_lds[part * 16 + jj], acc);
            acc = fmaf(bf2f((unsigned short)q1[jj]), kp_lds[part * 16 + 8 + jj], acc);
        }
        acc += __shfl_xor(acc, 1);
        acc += __shfl_xor(acc, 2);
        if (part == 0) den_qkp[s] = acc;
    }

    // --- QK^T: wave (sr = (w>>1)*16, th = w&1 -> t cols th*32..+32) ---
    const int sr = (w >> 1) * 16;
    const int th = w & 1;
    const int fr = lane & 15;
    const int fk = (lane >> 4) * 8;
    bf16x8 aq0 = *(bf16x8*)(Qb + SWZ(sr + fr, fk * 2));
    bf16x8 aq1 = *(bf16x8*)(Qb + SWZ(sr + fr, (32 + fk) * 2));
    f32x4 aqk[2] = {};
#pragma unroll
    for (int nt = 0; nt < 2; ++nt) {
        const int trow = th * 32 + nt * 16 + fr;
        bf16x8 bk0 = *(bf16x8*)(Kb + SWZ(trow, fk * 2));
        bf16x8 bk1 = *(bf16x8*)(Kb + SWZ(trow, (32 + fk) * 2));
        aqk[nt] = __builtin_amdgcn_mfma_f32_16x16x32_bf16(aq0, bk0, aqk[nt], 0, 0, 0);
        aqk[nt] = __builtin_amdgcn_mfma_f32_16x16x32_bf16(aq1, bk1, aqk[nt], 0, 0, 0);
    }
    // mask (t <= half*32 + s_local), write P bf16, row-sum partials
    float rs[4] = {0.f, 0.f, 0.f, 0.f};
    const int srow0 = sr + (lane >> 4) * 4;
#pragma unroll
    for (int nt = 0; nt < 2; ++nt) {
        const int t = th * 32 + nt * 16 + fr;
#pragma unroll
        for (int r = 0; r < 4; ++r) {
            const int s = srow0 + r;
            const float pv = (t <= half * 32 + s) ? aqk[nt][r] : 0.f;
            rs[r] += pv;
            *(unsigned short*)(Pb + SWZ(s, t * 2)) = f2bf(pv);
        }
    }
#pragma unroll
    for (int m = 1; m < 16; m <<= 1) {
        rs[0] += __shfl_xor(rs[0], m);
        rs[1] += __shfl_xor(rs[1], m);
        rs[2] += __shfl_xor(rs[2], m);
        rs[3] += __shfl_xor(rs[3], m);
    }
    if (fr == 0) {
#pragma unroll
        for (int r = 0; r < 4; ++r) den_qk[th][srow0 + r] = rs[r];
    }
    __syncthreads();

    // --- PV + QKVpre + mem (wave: s-tile sr, e-half eh = w&1) ---
    const int eh = w & 1;
    const float g = 1.f / (1.f + __expf(-gate[h]));
    const float gl = 1.f - g;
    const unsigned short* mb0 = mbT + (size_t)(0 * NHEAD + h) * 4096;
    const unsigned short* mb1 = mbT + (size_t)(1 * NHEAD + h) * 4096;
    const unsigned short* mb2 = mbT + (size_t)(2 * NHEAD + h) * 4096;
    const unsigned short* mb3 = mbT + (size_t)(3 * NHEAD + h) * 4096;
    bf16x8 ap0 = *(bf16x8*)(Pb + SWZ(sr + fr, fk * 2));
    bf16x8 ap1 = *(bf16x8*)(Pb + SWZ(sr + fr, (32 + fk) * 2));
#pragma unroll
    for (int nt = 0; nt < 2; ++nt) {
        const int er = eh * 32 + nt * 16 + fr;
        f32x4 lacc = {};
        bf16x8 bv0 = *(bf16x8*)(Vb + SWZ(er, fk * 2));
        bf16x8 bv1 = *(bf16x8*)(Vb + SWZ(er, (32 + fk) * 2));
        lacc = __builtin_amdgcn_mfma_f32_16x16x32_bf16(ap0, bv0, lacc, 0, 0, 0);
        lacc = __builtin_amdgcn_mfma_f32_16x16x32_bf16(ap1, bv1, lacc, 0, 0, 0);
        bf16x8 bkv0 = *(bf16x8*)(KVb + SWZ(er, fk * 2));
        bf16x8 bkv1 = *(bf16x8*)(KVb + SWZ(er, (32 + fk) * 2));
        lacc = __builtin_amdgcn_mfma_f32_16x16x32_bf16(aq0, bkv0, lacc, 0, 0, 0);
        lacc = __builtin_amdgcn_mfma_f32_16x16x32_bf16(aq1, bkv1, lacc, 0, 0, 0);

        const int mrow = er * 64;
        f32x4 macc = {};
        {
            f32x4 mm = {};
            mm = __builtin_amdgcn_mfma_f32_16x16x32_bf16(aq0, *(const bf16x8*)&mb0[mrow + fk], mm, 0, 0, 0);
            mm = __builtin_amdgcn_mfma_f32_16x16x32_bf16(aq1, *(const bf16x8*)&mb0[mrow + 32 + fk], mm, 0, 0, 0);
#pragma unroll
            for (int r = 0; r < 4; ++r) macc[r] = fmaf(c_lds[0][srow0 + r], mm[r], macc[r]);
        }
        {
            f32x4 mm = {};
            mm = __builtin_amdgcn_mfma_f32_16x16x32_bf16(aq0, *(const bf16x8*)&mb1[mrow + fk], mm, 0, 0, 0);
            mm = __builtin_amdgcn_mfma_f32_16x16x32_bf16(aq1, *(const bf16x8*)&mb1[mrow + 32 + fk], mm, 0, 0, 0);
#pragma unroll
            for (int r = 0; r < 4; ++r) macc[r] = fmaf(c_lds[1][srow0 + r], mm[r], macc[r]);
        }
        {
            f32x4 mm = {};
            mm = __builtin_amdgcn_mfma_f32_16x16x32_bf16(aq0, *(const bf16x8*)&mb2[mrow + fk], mm, 0, 0, 0);
            mm = __builtin_amdgcn_mfma_f32_16x16x32_bf16(aq1, *(const bf16x8*)&mb2[mrow + 32 + fk], mm, 0, 0, 0);
#pragma unroll
            for (int r = 0; r < 4; ++r) macc[r] = fmaf(c_lds[2][srow0 + r], mm[r], macc[r]);
        }
        {
            f32x4 mm = {};
            mm = __builtin_amdgcn_mfma_f32_16x16x32_bf16(aq0, *(const bf16x8*)&mb3[mrow + fk], mm, 0, 0, 0);
            mm = __builtin_amdgcn_mfma_f32_16x16x32_bf16(aq1, *(const bf16x8*)&mb3[mrow + 32 + fk], mm, 0, 0, 0);
#pragma unroll
            for (int r = 0; r < 4; ++r) macc[r] = fmaf(c_lds[3][srow0 + r], mm[r], macc[r]);
        }

        const int e = eh * 32 + nt * 16 + fr;
#pragma unroll
        for (int r = 0; r < 4; ++r) {
            const int s = srow0 + r;
            const float den = fmaxf(den_qkp[s] + den_qk[0][s] + den_qk[1][s], EPS_C);
            const float val = g * macc[r] + gl * lacc[r] / den;
            cb[(size_t)(s0 + s) * H_DIM + h * HD + e] = f2bf(val);
        }
    }
}

extern "C" void kernel_launch(void* const* d_in, const int* in_sizes, int n_in,
                              void* d_out, int out_size, void* d_ws, size_t ws_size,
                              hipStream_t stream) {
    const float* hidden   = (const float*)d_in[0];
    const float* w_q      = (const float*)d_in[1];
    const float* w_k      = (const float*)d_in[2];
    const float* w_v      = (const float*)d_in[3];
    const float* w_o      = (const float*)d_in[4];
    const float* gate     = (const float*)d_in[5];
    const float* memories = (const float*)d_in[6];
    const float* memnorms = (const float*)d_in[7];
    float* out = (float*)d_out;

    float* ws = (float*)d_ws;
    size_t off = 0;
    float* rel     = ws + off; off += (size_t)NMEM * NHEAD * S_LEN;
    float* relpart = ws + off; off += 256;
    float* cks     = ws + off; off += (size_t)NHEAD * NCHUNK * HD;
    float* cksc    = ws + off; off += (size_t)NHEAD * NCHUNK * HD;
    unsigned short* ckv_b  = (unsigned short*)(ws + off); off += (size_t)NHEAD * NCHUNK * HD * HD / 2;
    unsigned short* ckvT_b = (unsigned short*)(ws + off); off += (size_t)NHEAD * NCHUNK * HD * HD / 2;
    unsigned short* hb  = (unsigned short*)(ws + off); off += (size_t)S_LEN * H_DIM / 2;
    unsigned short* wb  = (unsigned short*)(ws + off); off += (size_t)3 * H_DIM * H_DIM / 2;
    unsigned short* wob = (unsigned short*)(ws + off); off += (size_t)H_DIM * H_DIM / 2;
    unsigned short* qb  = (unsigned short*)(ws + off); off += (size_t)S_LEN * H_DIM / 2;
    unsigned short* kb  = (unsigned short*)(ws + off); off += (size_t)S_LEN * H_DIM / 2;
    unsigned short* vb  = (unsigned short*)(ws + off); off += (size_t)S_LEN * H_DIM / 2;
    unsigned short* cb  = (unsigned short*)(ws + off); off += (size_t)S_LEN * H_DIM / 2;
    unsigned short* mbT = (unsigned short*)(ws + off); off += (size_t)NMEM * NHEAD * HD * HD / 2;

    // 1. conversions + memory transpose
    prep_kernel<<<3136, 256, 0, stream>>>(hidden, w_q, w_k, w_v, w_o, memories,
                                          hb, wb, wob, mbT);
    // 2. fused QKV projection (BM=64/BN=128/BK=64 dbuf, 768 blocks = 3/CU)
    gemm_mfma_kernel<1, 128><<<768, 256, 0, stream>>>(
        hb, wb, nullptr, qb, kb, vb, H_DIM, 3);
    // 3. per-chunk KV state + relevance (merged, 16x36 blocks)
    chunkkv_rel_kernel<<<dim3(NHEAD, 36), 256, 0, stream>>>(
        kb, vb, qb, memnorms, ckv_b, cksc, rel, relpart);
    // 4. exclusive prefix scan (upfront-load register scan, 128 blocks)
    prefix_kernel<<<dim3(NHEAD, 8), 256, 0, stream>>>(ckv_b, cksc, ckvT_b, cks);
    // 5. fused memory + local output (32-row tiles, 1024 blocks = 4/CU)
    fused_out_kernel<<<dim3(NHEAD, 2 * NCHUNK), 256, 0, stream>>>(
        qb, kb, vb, ckvT_b, cks, mbT, rel, relpart, gate, cb);
    // 6. output projection (BM=64/BN=64, 512 blocks = 2/CU)
    gemm_mfma_kernel<0, 64><<<512, 256, 0, stream>>>(
        cb, wob, out, nullptr, nullptr, nullptr, H_DIM, 2);
}

// Round 14
// 74.818 us; speedup vs baseline: 1.0453x; 1.0453x over previous
//
#include <hip/hip_runtime.h>
#include <hip/hip_bf16.h>
#include <math.h>

#define S_LEN 2048
#define H_DIM 1024
#define NHEAD 16
#define HD 64
#define NMEM 4
#define NCHUNK 32
#define CLEN 64
#define EPS_C 1e-6f

typedef __attribute__((ext_vector_type(8))) short bf16x8;
typedef __attribute__((ext_vector_type(4))) float f32x4;
typedef __attribute__((ext_vector_type(8))) unsigned short u16x8;
typedef __attribute__((ext_vector_type(4))) unsigned short u16x4;

__device__ __forceinline__ unsigned short f2bf(float f) {
    unsigned int u = __float_as_uint(f);
    u += 0x7FFFu + ((u >> 16) & 1u);   // round-to-nearest-even
    return (unsigned short)(u >> 16);
}
__device__ __forceinline__ float bf2f(unsigned short u) {
    return __uint_as_float((unsigned int)u << 16);
}

// swizzle for 64-col bf16 tiles, 128B rows (G4: byte ^= (row&7)<<4)
#define SWZ(row, colbyte) ((row) * 128 + ((colbyte) ^ (((row) & 7) << 4)))

// ---------------------------------------------------------------------------
// prep: all f32->bf16 conversions + memories transpose, one launch.
// ---------------------------------------------------------------------------
__global__ __launch_bounds__(256) void prep_kernel(const float* __restrict__ hidden,
                                                   const float* __restrict__ w_q,
                                                   const float* __restrict__ w_k,
                                                   const float* __restrict__ w_v,
                                                   const float* __restrict__ w_o,
                                                   const float* __restrict__ memories,
                                                   unsigned short* __restrict__ hb,
                                                   unsigned short* __restrict__ wb,
                                                   unsigned short* __restrict__ wob,
                                                   unsigned short* __restrict__ mbT) {
    const int b = blockIdx.x;
    const int tid = threadIdx.x;
    __shared__ float t[64][65];
    if (b < 3072) {
        const float* src;
        unsigned short* dst;
        int base;
        if (b < 1024)      { src = hidden; dst = hb;            base = b; }
        else if (b < 1536) { src = w_q;    dst = wb;            base = b - 1024; }
        else if (b < 2048) { src = w_k;    dst = wb + 1048576;  base = b - 1536; }
        else if (b < 2560) { src = w_v;    dst = wb + 2097152;  base = b - 2048; }
        else               { src = w_o;    dst = wob;           base = b - 2560; }
        const int i = base * 2048 + tid * 8;
        float4 a = *(const float4*)(src + i);
        float4 c = *(const float4*)(src + i + 4);
        u16x8 o;
        o[0] = f2bf(a.x); o[1] = f2bf(a.y); o[2] = f2bf(a.z); o[3] = f2bf(a.w);
        o[4] = f2bf(c.x); o[5] = f2bf(c.y); o[6] = f2bf(c.z); o[7] = f2bf(c.w);
        *(u16x8*)(dst + i) = o;
    } else {
        const int mh = b - 3072;
        const float* src = memories + (size_t)mh * 4096;
#pragma unroll
        for (int j = 0; j < 4; ++j) {
            const int idx = j * 1024 + tid * 4;
            *(float4*)&t[idx >> 6][idx & 63] = *(const float4*)&src[idx];
        }
        __syncthreads();
        unsigned short* dst = mbT + (size_t)mh * 4096;
#pragma unroll
        for (int j = 0; j < 4; ++j) {
            const int idx = j * 1024 + tid * 4;
            const int e = idx >> 6, d = idx & 63;
            u16x4 o;
#pragma unroll
            for (int i = 0; i < 4; ++i) o[i] = f2bf(t[d + i][e]);
            *(u16x4*)&dst[idx] = o;
        }
    }
}

// ---------------------------------------------------------------------------
// MFMA bf16 GEMM, BM=64 x BN(template), BK=64 (two 32-planes), double-buffered
// LDS, prefetch-before-compute (one barrier per K-tile). XCD-chunked 1D grid.
// MODE 0: f32 out (no act). MODE 1 (BN=128): qkv, bf16 out, elu1 on seg 0/1.
// ---------------------------------------------------------------------------
template <int MODE, int BN>
__global__ __launch_bounds__(256) void gemm_mfma_kernel(const unsigned short* __restrict__ A,
                                                        const unsigned short* __restrict__ B,
                                                        float* __restrict__ f32out,
                                                        unsigned short* __restrict__ b0,
                                                        unsigned short* __restrict__ b1,
                                                        unsigned short* __restrict__ b2,
                                                        int K, int perx) {
    constexpr int NNI = BN / 32;        // B col-frags per wave
    __shared__ unsigned short Als[2][2][64][32];    // buf, kplane, row, k
    __shared__ unsigned short Bls[2][2][BN][32];
    const int tid  = threadIdx.x;
    const int lane = tid & 63;
    const int wv   = tid >> 6;
    const int wr   = wv >> 1;
    const int wc   = wv & 1;
    const int d    = blockIdx.x;
    const int xcd  = d & 7;
    const int j    = d >> 3;
    const int y    = xcd * perx + (j >> 5);
    const int x    = j & 31;
    const int bm   = x * 64;
    const int bn   = y * BN;

    const int lrow = lane >> 2;
    const int skc  = (lane & 3) << 3;
    const unsigned short* gA = A + (size_t)(bm + (wv << 4) + lrow) * K + skc;
    const unsigned short* gB = B + (size_t)(bn + wv * (BN / 4) + lrow) * K + skc;

    const int frow = lane & 15;
    const int fkof = (lane >> 4) << 3;

    f32x4 acc[2][NNI] = {};

    auto stage = [&](int buf, int t) {
        const size_t ko = (size_t)t * 64;
#pragma unroll
        for (int pl = 0; pl < 2; ++pl) {
            __builtin_amdgcn_global_load_lds(
                (const __attribute__((address_space(1))) void*)(gA + ko + pl * 32),
                (__attribute__((address_space(3))) void*)&Als[buf][pl][wv << 4][0], 16, 0, 0);
#pragma unroll
            for (int q = 0; q < BN / 64; ++q)
                __builtin_amdgcn_global_load_lds(
                    (const __attribute__((address_space(1))) void*)(gB + (size_t)q * 16 * K + ko + pl * 32),
                    (__attribute__((address_space(3))) void*)&Bls[buf][pl][wv * (BN / 4) + q * 16][0], 16, 0, 0);
        }
    };

    const int NT = K >> 6;   // 16 for K=1024
    stage(0, 0);
    __syncthreads();
    int cur = 0;
    for (int t = 0; t < NT; ++t) {
        if (t + 1 < NT) stage(cur ^ 1, t + 1);   // prefetch next tile (overlaps compute)
        bf16x8 af[2][2], bf[2][NNI];
#pragma unroll
        for (int pl = 0; pl < 2; ++pl) {
#pragma unroll
            for (int mi = 0; mi < 2; ++mi)
                af[pl][mi] = *(const bf16x8*)&Als[cur][pl][wr * 32 + mi * 16 + frow][fkof];
#pragma unroll
            for (int ni = 0; ni < NNI; ++ni)
                bf[pl][ni] = *(const bf16x8*)&Bls[cur][pl][wc * (BN / 2) + ni * 16 + frow][fkof];
        }
#pragma unroll
        for (int pl = 0; pl < 2; ++pl)
#pragma unroll
            for (int mi = 0; mi < 2; ++mi)
#pragma unroll
                for (int ni = 0; ni < NNI; ++ni)
                    acc[mi][ni] = __builtin_amdgcn_mfma_f32_16x16x32_bf16(af[pl][mi], bf[pl][ni], acc[mi][ni], 0, 0, 0);
        __syncthreads();   // drains prefetch vmcnt + protects buf reuse
        cur ^= 1;
    }

    unsigned short* bdst = b0;
    int colbase = bn;
    bool act = false;
    if (MODE == 1) {
        const int seg = bn >> 10;
        bdst = (seg == 0) ? b0 : ((seg == 1) ? b1 : b2);
        colbase = bn & 1023;
        act = (seg < 2);
    }
    const int crow = (lane >> 4) << 2;
    const int ccol = lane & 15;
#pragma unroll
    for (int mi = 0; mi < 2; ++mi) {
#pragma unroll
        for (int ni = 0; ni < NNI; ++ni) {
            const int col = colbase + wc * (BN / 2) + ni * 16 + ccol;
#pragma unroll
            for (int r = 0; r < 4; ++r) {
                const int row = bm + wr * 32 + mi * 16 + crow + r;
                float xv = acc[mi][ni][r];
                if (MODE == 0) {
                    f32out[(size_t)row * 1024 + col] = xv;
                } else {
                    if (act) xv = (xv > 0.f) ? (xv + 1.f) : __expf(xv);
                    bdst[(size_t)row * 1024 + col] = f2bf(xv);
                }
            }
        }
    }
}

// ---------------------------------------------------------------------------
// chunkkv + rel merged kernel. grid (NHEAD, 36):
//   y <  32: chunkkv for chunk y  -> ckv_b (bf16), cksc
//   y >= 32: rel for s-segment (y-32)*512 -> rel, relpart
// ---------------------------------------------------------------------------
__global__ __launch_bounds__(256) void chunkkv_rel_kernel(const unsigned short* __restrict__ kb,
                                                          const unsigned short* __restrict__ vb,
                                                          const unsigned short* __restrict__ qb,
                                                          const float* __restrict__ norms,
                                                          unsigned short* __restrict__ ckv_b,
                                                          float* __restrict__ cksc,
                                                          float* __restrict__ rel,
                                                          float* __restrict__ relpart) {
    const int h = blockIdx.x;
    const int tid = threadIdx.x;
    __shared__ unsigned short KT[4096], VT[4096];
    __shared__ float red[256];

    if (blockIdx.y >= 32) {
        // ---------------- rel path ----------------
        const int seg = blockIdx.y - 32;
        float* nl = (float*)KT;          // reuse LDS: 4*64 floats
        {
            const int m = tid >> 6, dd = tid & 63;
            nl[m * 64 + dd] = norms[(size_t)(m * NHEAD + h) * HD + dd];
        }
        __syncthreads();
        float sums[4] = {0.f, 0.f, 0.f, 0.f};
#pragma unroll
        for (int it = 0; it < 2; ++it) {
            const int s = seg * 512 + it * 256 + tid;
            const unsigned short* row = qb + (size_t)s * H_DIM + h * HD;
            float dot[4] = {0.f, 0.f, 0.f, 0.f};
#pragma unroll
            for (int d0 = 0; d0 < 64; d0 += 8) {
                u16x8 v = *(const u16x8*)(row + d0);
#pragma unroll
                for (int i = 0; i < 8; ++i) {
                    const float qv = bf2f(v[i]);
                    dot[0] = fmaf(qv, nl[0 * 64 + d0 + i], dot[0]);
                    dot[1] = fmaf(qv, nl[1 * 64 + d0 + i], dot[1]);
                    dot[2] = fmaf(qv, nl[2 * 64 + d0 + i], dot[2]);
                    dot[3] = fmaf(qv, nl[3 * 64 + d0 + i], dot[3]);
                }
            }
#pragma unroll
            for (int m = 0; m < NMEM; ++m) {
                rel[(size_t)(m * NHEAD + h) * S_LEN + s] = dot[m];
                sums[m] += dot[m];
            }
        }
#pragma unroll
        for (int m = 0; m < NMEM; ++m) {
            red[tid] = sums[m];
            __syncthreads();
            for (int o = 128; o > 0; o >>= 1) {
                if (tid < o) red[tid] += red[tid + o];
                __syncthreads();
            }
            if (tid == 0) relpart[(m * NHEAD + h) * 4 + seg] = red[0];
            __syncthreads();
        }
        return;
    }

    // ---------------- chunkkv path ----------------
    const int c = blockIdx.y;
    const int s0 = c * CLEN;
    char* KTb = (char*)KT;
    char* VTb = (char*)VT;
    const int lane = tid & 63;
    const int w = tid >> 6;
    const int fr = lane & 15;
    const int fk = (lane >> 4) * 8;
    const int er = w * 16 + (lane >> 4) * 4;

    const int idx0 = tid * 8, idx1 = 2048 + tid * 8;
    const int r0 = idx0 >> 6, c0 = idx0 & 63;
    const int r1 = idx1 >> 6, c1 = idx1 & 63;

    u16x8 k0 = *(const u16x8*)&kb[(size_t)(s0 + r0) * H_DIM + h * HD + c0];
    u16x8 k1 = *(const u16x8*)&kb[(size_t)(s0 + r1) * H_DIM + h * HD + c1];
    u16x8 v0 = *(const u16x8*)&vb[(size_t)(s0 + r0) * H_DIM + h * HD + c0];
    u16x8 v1 = *(const u16x8*)&vb[(size_t)(s0 + r1) * H_DIM + h * HD + c1];
#pragma unroll
    for (int j = 0; j < 8; ++j) {
        *(unsigned short*)(KTb + SWZ(c0 + j, r0 * 2)) = (unsigned short)k0[j];
        *(unsigned short*)(KTb + SWZ(c1 + j, r1 * 2)) = (unsigned short)k1[j];
        *(unsigned short*)(VTb + SWZ(c0 + j, r0 * 2)) = (unsigned short)v0[j];
        *(unsigned short*)(VTb + SWZ(c1 + j, r1 * 2)) = (unsigned short)v1[j];
    }
    __syncthreads();

    bf16x8 a0 = *(bf16x8*)(VTb + SWZ(w * 16 + fr, fk * 2));
    bf16x8 a1 = *(bf16x8*)(VTb + SWZ(w * 16 + fr, (32 + fk) * 2));
    f32x4 acc[4] = {};
    bf16x8 ones;
#pragma unroll
    for (int i = 0; i < 8; ++i) ones[i] = (short)0x3F80;
    bf16x8 bw0 = *(bf16x8*)(KTb + SWZ(w * 16 + fr, fk * 2));
    bf16x8 bw1 = *(bf16x8*)(KTb + SWZ(w * 16 + fr, (32 + fk) * 2));
    f32x4 ka = {};
    ka = __builtin_amdgcn_mfma_f32_16x16x32_bf16(ones, bw0, ka, 0, 0, 0);
    ka = __builtin_amdgcn_mfma_f32_16x16x32_bf16(ones, bw1, ka, 0, 0, 0);
#pragma unroll
    for (int nt = 0; nt < 4; ++nt) {
        bf16x8 b0 = *(bf16x8*)(KTb + SWZ(nt * 16 + fr, fk * 2));
        bf16x8 b1 = *(bf16x8*)(KTb + SWZ(nt * 16 + fr, (32 + fk) * 2));
        acc[nt] = __builtin_amdgcn_mfma_f32_16x16x32_bf16(a0, b0, acc[nt], 0, 0, 0);
        acc[nt] = __builtin_amdgcn_mfma_f32_16x16x32_bf16(a1, b1, acc[nt], 0, 0, 0);
    }

    unsigned short* dst = ckv_b + ((size_t)(h * NCHUNK + c) << 12);
#pragma unroll
    for (int nt = 0; nt < 4; ++nt) {
        const int dd = nt * 16 + fr;
#pragma unroll
        for (int r = 0; r < 4; ++r)
            dst[(er + r) * 64 + dd] = f2bf(acc[nt][r]);
    }
    if (lane < 16)
        cksc[(size_t)(h * NCHUNK + c) * HD + w * 16 + lane] = ka[0];
}

// ---------------------------------------------------------------------------
// prefix: exclusive scan over chunks. All 32 chunk values loaded upfront.
// ---------------------------------------------------------------------------
__global__ __launch_bounds__(256) void prefix_kernel(const unsigned short* __restrict__ ckv_b,
                                                     const float* __restrict__ cksc,
                                                     unsigned short* __restrict__ ckvT_b,
                                                     float* __restrict__ cks) {
    const int h = blockIdx.x;
    const int g = blockIdx.y;
    const int tid = threadIdx.x;
    const int fo = g * 512 + tid * 2;
    const size_t base = ((size_t)(h * NCHUNK)) << 12;
    unsigned int vals[NCHUNK];
#pragma unroll
    for (int c = 0; c < NCHUNK; ++c)
        vals[c] = *(const unsigned int*)&ckv_b[base + ((size_t)c << 12) + fo];
    float rx = 0.f, ry = 0.f;
#pragma unroll
    for (int c = 0; c < NCHUNK; ++c) {
        *(unsigned int*)&ckvT_b[base + ((size_t)c << 12) + fo] =
            ((unsigned int)f2bf(ry) << 16) | (unsigned int)f2bf(rx);
        rx += bf2f((unsigned short)(vals[c] & 0xFFFF));
        ry += bf2f((unsigned short)(vals[c] >> 16));
    }
    if (g == 0 && tid < 64) {
        float kv[NCHUNK];
#pragma unroll
        for (int c = 0; c < NCHUNK; ++c)
            kv[c] = cksc[(size_t)(h * NCHUNK + c) * HD + tid];
        float rk = 0.f;
#pragma unroll
        for (int c = 0; c < NCHUNK; ++c) {
            cks[(size_t)(h * NCHUNK + c) * HD + tid] = rk;
            rk += kv[c];
        }
    }
}

// ---------------------------------------------------------------------------
// Fused output kernel for one (head, chunk): memory retrieval + causal local
// attention, all MFMA. M fragments read directly from L2 (no LDS staging).
// s_setprio(1) around MFMA clusters (T5: independent blocks, staggered phases).
// ---------------------------------------------------------------------------
__global__ __launch_bounds__(256) void fused_out_kernel(const unsigned short* __restrict__ qb,
                                                        const unsigned short* __restrict__ kb,
                                                        const unsigned short* __restrict__ vb,
                                                        const unsigned short* __restrict__ ckvT_b,
                                                        const float* __restrict__ cks,
                                                        const unsigned short* __restrict__ mbT,
                                                        const float* __restrict__ rel,
                                                        const float* __restrict__ relpart,
                                                        const float* __restrict__ gate,
                                                        unsigned short* __restrict__ cb) {
    const int h = blockIdx.x;
    const int c = blockIdx.y;
    const int s0 = c * CLEN;
    __shared__ unsigned short Qs[4096], Ks[4096], VsT[4096], KVsT[4096], Ps[4096];
    __shared__ float kp_lds[64];
    __shared__ float den_lds[64];
    __shared__ float c_lds[4][64];
    char* Qb  = (char*)Qs;
    char* Kb  = (char*)Ks;
    char* Vb  = (char*)VsT;
    char* KVb = (char*)KVsT;
    char* Pb  = (char*)Ps;
    const int tid = threadIdx.x;
    const int lane = tid & 63;
    const int w = tid >> 6;

    // --- stage Q, K (row-major), V (transposed) ---
#pragma unroll
    for (int p = 0; p < 2; ++p) {
        const int idx = p * 2048 + tid * 8;
        const int r = idx >> 6, cc = idx & 63;
        const size_t gidx = (size_t)(s0 + r) * H_DIM + h * HD + cc;
        u16x8 q8 = *(const u16x8*)&qb[gidx];
        u16x8 k8 = *(const u16x8*)&kb[gidx];
        u16x8 v8 = *(const u16x8*)&vb[gidx];
        *(u16x8*)(Qb + SWZ(r, cc * 2)) = q8;
        *(u16x8*)(Kb + SWZ(r, cc * 2)) = k8;
#pragma unroll
        for (int j = 0; j < 8; ++j)
            *(unsigned short*)(Vb + SWZ(cc + j, r * 2)) = (unsigned short)v8[j];
    }
    // --- stage KVpre^T (bf16, already [e][d]) ---
    const unsigned short* kvsrc = ckvT_b + ((size_t)(h * NCHUNK + c) << 12);
#pragma unroll
    for (int p = 0; p < 2; ++p) {
        const int idx = p * 2048 + tid * 8;
        const int e = idx >> 6, d = idx & 63;
        *(u16x8*)(KVb + SWZ(e, d * 2)) = *(const u16x8*)&kvsrc[idx];
    }
    if (tid < 64) kp_lds[tid] = cks[(size_t)(h * NCHUNK + c) * HD + tid];
    {
        // inline softmax weights over memories (from 4-segment partials)
        const int m = tid >> 6, si = tid & 63;
        float v[NMEM], mx = -1e30f;
#pragma unroll
        for (int mm = 0; mm < NMEM; ++mm) {
            const float* rp = &relpart[(mm * NHEAD + h) * 4];
            v[mm] = (rp[0] + rp[1] + rp[2] + rp[3]) * (1.f / (float)S_LEN);
            mx = fmaxf(mx, v[mm]);
        }
        float sum = 0.f;
#pragma unroll
        for (int mm = 0; mm < NMEM; ++mm) { v[mm] = __expf(v[mm] - mx); sum += v[mm]; }
        const float wgt = v[m] / sum;
        c_lds[m][si] = wgt / fmaxf(rel[(size_t)(m * NHEAD + h) * S_LEN + s0 + si], EPS_C);
    }
    __syncthreads();

    // --- den_init[s] = q[s]·kpre (vectorized LDS reads) ---
    {
        const int s = tid >> 2, part = tid & 3;
        bf16x8 q0 = *(bf16x8*)(Qb + SWZ(s, (part * 16) * 2));
        bf16x8 q1 = *(bf16x8*)(Qb + SWZ(s, (part * 16 + 8) * 2));
        float acc = 0.f;
#pragma unroll
        for (int jj = 0; jj < 8; ++jj) {
            acc = fmaf(bf2f((unsigned short)q0[jj]), kp_lds[part * 16 + jj], acc);
            acc = fmaf(bf2f((unsigned short)q1[jj]), kp_lds[part * 16 + 8 + jj], acc);
        }
        acc += __shfl_xor(acc, 1);
        acc += __shfl_xor(acc, 2);
        if (part == 0) den_lds[s] = acc;
    }

    // --- QK^T ---
    const int sb = w * 16;
    const int fr = lane & 15;
    const int fk = (lane >> 4) * 8;
    bf16x8 aq0 = *(bf16x8*)(Qb + SWZ(sb + fr, fk * 2));
    bf16x8 aq1 = *(bf16x8*)(Qb + SWZ(sb + fr, (32 + fk) * 2));
    f32x4 aqk[4] = {};
    __builtin_amdgcn_s_setprio(1);
#pragma unroll
    for (int nt = 0; nt < 4; ++nt) {
        bf16x8 bk0 = *(bf16x8*)(Kb + SWZ(nt * 16 + fr, fk * 2));
        bf16x8 bk1 = *(bf16x8*)(Kb + SWZ(nt * 16 + fr, (32 + fk) * 2));
        aqk[nt] = __builtin_amdgcn_mfma_f32_16x16x32_bf16(aq0, bk0, aqk[nt], 0, 0, 0);
        aqk[nt] = __builtin_amdgcn_mfma_f32_16x16x32_bf16(aq1, bk1, aqk[nt], 0, 0, 0);
    }
    __builtin_amdgcn_s_setprio(0);
    // mask (t<=s), write P bf16, accumulate row sums
    float rs[4] = {0.f, 0.f, 0.f, 0.f};
    const int srow0 = sb + (lane >> 4) * 4;
#pragma unroll
    for (int nt = 0; nt < 4; ++nt) {
        const int t = nt * 16 + fr;
#pragma unroll
        for (int r = 0; r < 4; ++r) {
            const int s = srow0 + r;
            const float pv = (t <= s) ? aqk[nt][r] : 0.f;
            rs[r] += pv;
            *(unsigned short*)(Pb + SWZ(s, t * 2)) = f2bf(pv);
        }
    }
#pragma unroll
    for (int m = 1; m < 16; m <<= 1) {
        rs[0] += __shfl_xor(rs[0], m);
        rs[1] += __shfl_xor(rs[1], m);
        rs[2] += __shfl_xor(rs[2], m);
        rs[3] += __shfl_xor(rs[3], m);
    }
    if (fr == 0) {
#pragma unroll
        for (int r = 0; r < 4; ++r) den_lds[srow0 + r] += rs[r];
    }
    __syncthreads();

    // --- num = P@V + Q@KVpre; mem = sum_m c_m * (Q@M_m^T direct from L2) ---
    const float g = 1.f / (1.f + __expf(-gate[h]));
    const float gl = 1.f - g;
    const unsigned short* mb0 = mbT + (size_t)(0 * NHEAD + h) * 4096;
    const unsigned short* mb1 = mbT + (size_t)(1 * NHEAD + h) * 4096;
    const unsigned short* mb2 = mbT + (size_t)(2 * NHEAD + h) * 4096;
    const unsigned short* mb3 = mbT + (size_t)(3 * NHEAD + h) * 4096;
#pragma unroll
    for (int nt = 0; nt < 4; ++nt) {
        const int br = nt * 16 + fr;
        f32x4 lacc = {};
        bf16x8 ap0 = *(bf16x8*)(Pb + SWZ(sb + fr, fk * 2));
        bf16x8 ap1 = *(bf16x8*)(Pb + SWZ(sb + fr, (32 + fk) * 2));
        bf16x8 bv0 = *(bf16x8*)(Vb + SWZ(br, fk * 2));
        bf16x8 bv1 = *(bf16x8*)(Vb + SWZ(br, (32 + fk) * 2));
        bf16x8 bkv0 = *(bf16x8*)(KVb + SWZ(br, fk * 2));
        bf16x8 bkv1 = *(bf16x8*)(KVb + SWZ(br, (32 + fk) * 2));
        __builtin_amdgcn_s_setprio(1);
        lacc = __builtin_amdgcn_mfma_f32_16x16x32_bf16(ap0, bv0, lacc, 0, 0, 0);
        lacc = __builtin_amdgcn_mfma_f32_16x16x32_bf16(ap1, bv1, lacc, 0, 0, 0);
        lacc = __builtin_amdgcn_mfma_f32_16x16x32_bf16(aq0, bkv0, lacc, 0, 0, 0);
        lacc = __builtin_amdgcn_mfma_f32_16x16x32_bf16(aq1, bkv1, lacc, 0, 0, 0);
        __builtin_amdgcn_s_setprio(0);

        const int mrow = br * 64;
        f32x4 macc = {};
        {
            f32x4 mm = {};
            mm = __builtin_amdgcn_mfma_f32_16x16x32_bf16(aq0, *(const bf16x8*)&mb0[mrow + fk], mm, 0, 0, 0);
            mm = __builtin_amdgcn_mfma_f32_16x16x32_bf16(aq1, *(const bf16x8*)&mb0[mrow + 32 + fk], mm, 0, 0, 0);
#pragma unroll
            for (int r = 0; r < 4; ++r) macc[r] = fmaf(c_lds[0][srow0 + r], mm[r], macc[r]);
        }
        {
            f32x4 mm = {};
            mm = __builtin_amdgcn_mfma_f32_16x16x32_bf16(aq0, *(const bf16x8*)&mb1[mrow + fk], mm, 0, 0, 0);
            mm = __builtin_amdgcn_mfma_f32_16x16x32_bf16(aq1, *(const bf16x8*)&mb1[mrow + 32 + fk], mm, 0, 0, 0);
#pragma unroll
            for (int r = 0; r < 4; ++r) macc[r] = fmaf(c_lds[1][srow0 + r], mm[r], macc[r]);
        }
        {
            f32x4 mm = {};
            mm = __builtin_amdgcn_mfma_f32_16x16x32_bf16(aq0, *(const bf16x8*)&mb2[mrow + fk], mm, 0, 0, 0);
            mm = __builtin_amdgcn_mfma_f32_16x16x32_bf16(aq1, *(const bf16x8*)&mb2[mrow + 32 + fk], mm, 0, 0, 0);
#pragma unroll
            for (int r = 0; r < 4; ++r) macc[r] = fmaf(c_lds[2][srow0 + r], mm[r], macc[r]);
        }
        {
            f32x4 mm = {};
            mm = __builtin_amdgcn_mfma_f32_16x16x32_bf16(aq0, *(const bf16x8*)&mb3[mrow + fk], mm, 0, 0, 0);
            mm = __builtin_amdgcn_mfma_f32_16x16x32_bf16(aq1, *(const bf16x8*)&mb3[mrow + 32 + fk], mm, 0, 0, 0);
#pragma unroll
            for (int r = 0; r < 4; ++r) macc[r] = fmaf(c_lds[3][srow0 + r], mm[r], macc[r]);
        }

        const int e = nt * 16 + fr;
#pragma unroll
        for (int r = 0; r < 4; ++r) {
            const int s = srow0 + r;
            const float den = fmaxf(den_lds[s], EPS_C);
            const float val = g * macc[r] + gl * lacc[r] / den;
            cb[(size_t)(s0 + s) * H_DIM + h * HD + e] = f2bf(val);
        }
    }
}

extern "C" void kernel_launch(void* const* d_in, const int* in_sizes, int n_in,
                              void* d_out, int out_size, void* d_ws, size_t ws_size,
                              hipStream_t stream) {
    const float* hidden   = (const float*)d_in[0];
    const float* w_q      = (const float*)d_in[1];
    const float* w_k      = (const float*)d_in[2];
    const float* w_v      = (const float*)d_in[3];
    const float* w_o      = (const float*)d_in[4];
    const float* gate     = (const float*)d_in[5];
    const float* memories = (const float*)d_in[6];
    const float* memnorms = (const float*)d_in[7];
    float* out = (float*)d_out;

    float* ws = (float*)d_ws;
    size_t off = 0;
    float* rel     = ws + off; off += (size_t)NMEM * NHEAD * S_LEN;
    float* relpart = ws + off; off += 256;
    float* cks     = ws + off; off += (size_t)NHEAD * NCHUNK * HD;
    float* cksc    = ws + off; off += (size_t)NHEAD * NCHUNK * HD;
    unsigned short* ckv_b  = (unsigned short*)(ws + off); off += (size_t)NHEAD * NCHUNK * HD * HD / 2;
    unsigned short* ckvT_b = (unsigned short*)(ws + off); off += (size_t)NHEAD * NCHUNK * HD * HD / 2;
    unsigned short* hb  = (unsigned short*)(ws + off); off += (size_t)S_LEN * H_DIM / 2;
    unsigned short* wb  = (unsigned short*)(ws + off); off += (size_t)3 * H_DIM * H_DIM / 2;
    unsigned short* wob = (unsigned short*)(ws + off); off += (size_t)H_DIM * H_DIM / 2;
    unsigned short* qb  = (unsigned short*)(ws + off); off += (size_t)S_LEN * H_DIM / 2;
    unsigned short* kb  = (unsigned short*)(ws + off); off += (size_t)S_LEN * H_DIM / 2;
    unsigned short* vb  = (unsigned short*)(ws + off); off += (size_t)S_LEN * H_DIM / 2;
    unsigned short* cb  = (unsigned short*)(ws + off); off += (size_t)S_LEN * H_DIM / 2;
    unsigned short* mbT = (unsigned short*)(ws + off); off += (size_t)NMEM * NHEAD * HD * HD / 2;

    // 1. conversions + memory transpose
    prep_kernel<<<3136, 256, 0, stream>>>(hidden, w_q, w_k, w_v, w_o, memories,
                                          hb, wb, wob, mbT);
    // 2. fused QKV projection (BM=64/BN=128/BK=64 dbuf, 768 blocks = 3/CU)
    gemm_mfma_kernel<1, 128><<<768, 256, 0, stream>>>(
        hb, wb, nullptr, qb, kb, vb, H_DIM, 3);
    // 3. per-chunk KV state + relevance (merged, 16x36 blocks)
    chunkkv_rel_kernel<<<dim3(NHEAD, 36), 256, 0, stream>>>(
        kb, vb, qb, memnorms, ckv_b, cksc, rel, relpart);
    // 4. exclusive prefix scan (upfront-load register scan, 128 blocks)
    prefix_kernel<<<dim3(NHEAD, 8), 256, 0, stream>>>(ckv_b, cksc, ckvT_b, cks);
    // 5. fused memory + local output (64-row tiles, M direct from L2)
    fused_out_kernel<<<dim3(NHEAD, NCHUNK), 256, 0, stream>>>(
        qb, kb, vb, ckvT_b, cks, mbT, rel, relpart, gate, cb);
    // 6. output projection (BM=64/BN=64, 512 blocks = 2/CU)
    gemm_mfma_kernel<0, 64><<<512, 256, 0, stream>>>(
        cb, wob, out, nullptr, nullptr, nullptr, H_DIM, 2);
}

// Round 15
// 74.493 us; speedup vs baseline: 1.0498x; 1.0044x over previous
//
#include <hip/hip_runtime.h>
#include <hip/hip_bf16.h>
#include <math.h>

#define S_LEN 2048
#define H_DIM 1024
#define NHEAD 16
#define HD 64
#define NMEM 4
#define NCHUNK 32
#define CLEN 64
#define EPS_C 1e-6f

typedef __attribute__((ext_vector_type(8))) short bf16x8;
typedef __attribute__((ext_vector_type(4))) float f32x4;
typedef __attribute__((ext_vector_type(8))) unsigned short u16x8;
typedef __attribute__((ext_vector_type(4))) unsigned short u16x4;

__device__ __forceinline__ unsigned short f2bf(float f) {
    unsigned int u = __float_as_uint(f);
    u += 0x7FFFu + ((u >> 16) & 1u);   // round-to-nearest-even
    return (unsigned short)(u >> 16);
}
__device__ __forceinline__ float bf2f(unsigned short u) {
    return __uint_as_float((unsigned int)u << 16);
}

// swizzle for 64-col bf16 tiles, 128B rows (G4: byte ^= (row&7)<<4)
#define SWZ(row, colbyte) ((row) * 128 + ((colbyte) ^ (((row) & 7) << 4)))

// ---------------------------------------------------------------------------
// prep: all f32->bf16 conversions + memories transpose, one launch.
// ---------------------------------------------------------------------------
__global__ __launch_bounds__(256) void prep_kernel(const float* __restrict__ hidden,
                                                   const float* __restrict__ w_q,
                                                   const float* __restrict__ w_k,
                                                   const float* __restrict__ w_v,
                                                   const float* __restrict__ w_o,
                                                   const float* __restrict__ memories,
                                                   unsigned short* __restrict__ hb,
                                                   unsigned short* __restrict__ wb,
                                                   unsigned short* __restrict__ wob,
                                                   unsigned short* __restrict__ mbT) {
    const int b = blockIdx.x;
    const int tid = threadIdx.x;
    __shared__ float t[64][65];
    if (b < 3072) {
        const float* src;
        unsigned short* dst;
        int base;
        if (b < 1024)      { src = hidden; dst = hb;            base = b; }
        else if (b < 1536) { src = w_q;    dst = wb;            base = b - 1024; }
        else if (b < 2048) { src = w_k;    dst = wb + 1048576;  base = b - 1536; }
        else if (b < 2560) { src = w_v;    dst = wb + 2097152;  base = b - 2048; }
        else               { src = w_o;    dst = wob;           base = b - 2560; }
        const int i = base * 2048 + tid * 8;
        float4 a = *(const float4*)(src + i);
        float4 c = *(const float4*)(src + i + 4);
        u16x8 o;
        o[0] = f2bf(a.x); o[1] = f2bf(a.y); o[2] = f2bf(a.z); o[3] = f2bf(a.w);
        o[4] = f2bf(c.x); o[5] = f2bf(c.y); o[6] = f2bf(c.z); o[7] = f2bf(c.w);
        *(u16x8*)(dst + i) = o;
    } else {
        const int mh = b - 3072;
        const float* src = memories + (size_t)mh * 4096;
#pragma unroll
        for (int j = 0; j < 4; ++j) {
            const int idx = j * 1024 + tid * 4;
            *(float4*)&t[idx >> 6][idx & 63] = *(const float4*)&src[idx];
        }
        __syncthreads();
        unsigned short* dst = mbT + (size_t)mh * 4096;
#pragma unroll
        for (int j = 0; j < 4; ++j) {
            const int idx = j * 1024 + tid * 4;
            const int e = idx >> 6, d = idx & 63;
            u16x4 o;
#pragma unroll
            for (int i = 0; i < 4; ++i) o[i] = f2bf(t[d + i][e]);
            *(u16x4*)&dst[idx] = o;
        }
    }
}

// ---------------------------------------------------------------------------
// MFMA bf16 GEMM, BM=64 x BN(template), BK=64 (two 32-planes), double-buffered
// LDS, prefetch-before-compute (one barrier per K-tile). XCD-chunked 1D grid.
// MODE 0: f32 out (no act). MODE 1 (BN=128): qkv, bf16 out, elu1 on seg 0/1.
// ---------------------------------------------------------------------------
template <int MODE, int BN>
__global__ __launch_bounds__(256) void gemm_mfma_kernel(const unsigned short* __restrict__ A,
                                                        const unsigned short* __restrict__ B,
                                                        float* __restrict__ f32out,
                                                        unsigned short* __restrict__ b0,
                                                        unsigned short* __restrict__ b1,
                                                        unsigned short* __restrict__ b2,
                                                        int K, int perx) {
    constexpr int NNI = BN / 32;        // B col-frags per wave
    __shared__ unsigned short Als[2][2][64][32];    // buf, kplane, row, k
    __shared__ unsigned short Bls[2][2][BN][32];
    const int tid  = threadIdx.x;
    const int lane = tid & 63;
    const int wv   = tid >> 6;
    const int wr   = wv >> 1;
    const int wc   = wv & 1;
    const int d    = blockIdx.x;
    const int xcd  = d & 7;
    const int j    = d >> 3;
    const int y    = xcd * perx + (j >> 5);
    const int x    = j & 31;
    const int bm   = x * 64;
    const int bn   = y * BN;

    const int lrow = lane >> 2;
    const int skc  = (lane & 3) << 3;
    const unsigned short* gA = A + (size_t)(bm + (wv << 4) + lrow) * K + skc;
    const unsigned short* gB = B + (size_t)(bn + wv * (BN / 4) + lrow) * K + skc;

    const int frow = lane & 15;
    const int fkof = (lane >> 4) << 3;

    f32x4 acc[2][NNI] = {};

    auto stage = [&](int buf, int t) {
        const size_t ko = (size_t)t * 64;
#pragma unroll
        for (int pl = 0; pl < 2; ++pl) {
            __builtin_amdgcn_global_load_lds(
                (const __attribute__((address_space(1))) void*)(gA + ko + pl * 32),
                (__attribute__((address_space(3))) void*)&Als[buf][pl][wv << 4][0], 16, 0, 0);
#pragma unroll
            for (int q = 0; q < BN / 64; ++q)
                __builtin_amdgcn_global_load_lds(
                    (const __attribute__((address_space(1))) void*)(gB + (size_t)q * 16 * K + ko + pl * 32),
                    (__attribute__((address_space(3))) void*)&Bls[buf][pl][wv * (BN / 4) + q * 16][0], 16, 0, 0);
        }
    };

    const int NT = K >> 6;   // 16 for K=1024
    stage(0, 0);
    __syncthreads();
    int cur = 0;
    for (int t = 0; t < NT; ++t) {
        if (t + 1 < NT) stage(cur ^ 1, t + 1);   // prefetch next tile (overlaps compute)
        bf16x8 af[2][2], bf[2][NNI];
#pragma unroll
        for (int pl = 0; pl < 2; ++pl) {
#pragma unroll
            for (int mi = 0; mi < 2; ++mi)
                af[pl][mi] = *(const bf16x8*)&Als[cur][pl][wr * 32 + mi * 16 + frow][fkof];
#pragma unroll
            for (int ni = 0; ni < NNI; ++ni)
                bf[pl][ni] = *(const bf16x8*)&Bls[cur][pl][wc * (BN / 2) + ni * 16 + frow][fkof];
        }
#pragma unroll
        for (int pl = 0; pl < 2; ++pl)
#pragma unroll
            for (int mi = 0; mi < 2; ++mi)
#pragma unroll
                for (int ni = 0; ni < NNI; ++ni)
                    acc[mi][ni] = __builtin_amdgcn_mfma_f32_16x16x32_bf16(af[pl][mi], bf[pl][ni], acc[mi][ni], 0, 0, 0);
        __syncthreads();   // drains prefetch vmcnt + protects buf reuse
        cur ^= 1;
    }

    unsigned short* bdst = b0;
    int colbase = bn;
    bool act = false;
    if (MODE == 1) {
        const int seg = bn >> 10;
        bdst = (seg == 0) ? b0 : ((seg == 1) ? b1 : b2);
        colbase = bn & 1023;
        act = (seg < 2);
    }
    const int crow = (lane >> 4) << 2;
    const int ccol = lane & 15;
#pragma unroll
    for (int mi = 0; mi < 2; ++mi) {
#pragma unroll
        for (int ni = 0; ni < NNI; ++ni) {
            const int col = colbase + wc * (BN / 2) + ni * 16 + ccol;
#pragma unroll
            for (int r = 0; r < 4; ++r) {
                const int row = bm + wr * 32 + mi * 16 + crow + r;
                float xv = acc[mi][ni][r];
                if (MODE == 0) {
                    f32out[(size_t)row * 1024 + col] = xv;
                } else {
                    if (act) xv = (xv > 0.f) ? (xv + 1.f) : __expf(xv);
                    bdst[(size_t)row * 1024 + col] = f2bf(xv);
                }
            }
        }
    }
}

// ---------------------------------------------------------------------------
// chunkkv + rel merged kernel. grid (NHEAD, 36):
//   y <  32: chunkkv for chunk y  -> ckv_b (bf16), cksc
//   y >= 32: rel for s-segment (y-32)*512 -> rel, relpart
// ---------------------------------------------------------------------------
__global__ __launch_bounds__(256) void chunkkv_rel_kernel(const unsigned short* __restrict__ kb,
                                                          const unsigned short* __restrict__ vb,
                                                          const unsigned short* __restrict__ qb,
                                                          const float* __restrict__ norms,
                                                          unsigned short* __restrict__ ckv_b,
                                                          float* __restrict__ cksc,
                                                          float* __restrict__ rel,
                                                          float* __restrict__ relpart) {
    const int h = blockIdx.x;
    const int tid = threadIdx.x;
    __shared__ unsigned short KT[4096], VT[4096];
    __shared__ float red[256];

    if (blockIdx.y >= 32) {
        // ---------------- rel path ----------------
        const int seg = blockIdx.y - 32;
        float* nl = (float*)KT;          // reuse LDS: 4*64 floats
        {
            const int m = tid >> 6, dd = tid & 63;
            nl[m * 64 + dd] = norms[(size_t)(m * NHEAD + h) * HD + dd];
        }
        __syncthreads();
        float sums[4] = {0.f, 0.f, 0.f, 0.f};
#pragma unroll
        for (int it = 0; it < 2; ++it) {
            const int s = seg * 512 + it * 256 + tid;
            const unsigned short* row = qb + (size_t)s * H_DIM + h * HD;
            float dot[4] = {0.f, 0.f, 0.f, 0.f};
#pragma unroll
            for (int d0 = 0; d0 < 64; d0 += 8) {
                u16x8 v = *(const u16x8*)(row + d0);
#pragma unroll
                for (int i = 0; i < 8; ++i) {
                    const float qv = bf2f(v[i]);
                    dot[0] = fmaf(qv, nl[0 * 64 + d0 + i], dot[0]);
                    dot[1] = fmaf(qv, nl[1 * 64 + d0 + i], dot[1]);
                    dot[2] = fmaf(qv, nl[2 * 64 + d0 + i], dot[2]);
                    dot[3] = fmaf(qv, nl[3 * 64 + d0 + i], dot[3]);
                }
            }
#pragma unroll
            for (int m = 0; m < NMEM; ++m) {
                rel[(size_t)(m * NHEAD + h) * S_LEN + s] = dot[m];
                sums[m] += dot[m];
            }
        }
#pragma unroll
        for (int m = 0; m < NMEM; ++m) {
            red[tid] = sums[m];
            __syncthreads();
            for (int o = 128; o > 0; o >>= 1) {
                if (tid < o) red[tid] += red[tid + o];
                __syncthreads();
            }
            if (tid == 0) relpart[(m * NHEAD + h) * 4 + seg] = red[0];
            __syncthreads();
        }
        return;
    }

    // ---------------- chunkkv path ----------------
    const int c = blockIdx.y;
    const int s0 = c * CLEN;
    char* KTb = (char*)KT;
    char* VTb = (char*)VT;
    const int lane = tid & 63;
    const int w = tid >> 6;
    const int fr = lane & 15;
    const int fk = (lane >> 4) * 8;
    const int er = w * 16 + (lane >> 4) * 4;

    const int idx0 = tid * 8, idx1 = 2048 + tid * 8;
    const int r0 = idx0 >> 6, c0 = idx0 & 63;
    const int r1 = idx1 >> 6, c1 = idx1 & 63;

    u16x8 k0 = *(const u16x8*)&kb[(size_t)(s0 + r0) * H_DIM + h * HD + c0];
    u16x8 k1 = *(const u16x8*)&kb[(size_t)(s0 + r1) * H_DIM + h * HD + c1];
    u16x8 v0 = *(const u16x8*)&vb[(size_t)(s0 + r0) * H_DIM + h * HD + c0];
    u16x8 v1 = *(const u16x8*)&vb[(size_t)(s0 + r1) * H_DIM + h * HD + c1];
#pragma unroll
    for (int j = 0; j < 8; ++j) {
        *(unsigned short*)(KTb + SWZ(c0 + j, r0 * 2)) = (unsigned short)k0[j];
        *(unsigned short*)(KTb + SWZ(c1 + j, r1 * 2)) = (unsigned short)k1[j];
        *(unsigned short*)(VTb + SWZ(c0 + j, r0 * 2)) = (unsigned short)v0[j];
        *(unsigned short*)(VTb + SWZ(c1 + j, r1 * 2)) = (unsigned short)v1[j];
    }
    __syncthreads();

    bf16x8 a0 = *(bf16x8*)(VTb + SWZ(w * 16 + fr, fk * 2));
    bf16x8 a1 = *(bf16x8*)(VTb + SWZ(w * 16 + fr, (32 + fk) * 2));
    f32x4 acc[4] = {};
    bf16x8 ones;
#pragma unroll
    for (int i = 0; i < 8; ++i) ones[i] = (short)0x3F80;
    bf16x8 bw0 = *(bf16x8*)(KTb + SWZ(w * 16 + fr, fk * 2));
    bf16x8 bw1 = *(bf16x8*)(KTb + SWZ(w * 16 + fr, (32 + fk) * 2));
    f32x4 ka = {};
    ka = __builtin_amdgcn_mfma_f32_16x16x32_bf16(ones, bw0, ka, 0, 0, 0);
    ka = __builtin_amdgcn_mfma_f32_16x16x32_bf16(ones, bw1, ka, 0, 0, 0);
#pragma unroll
    for (int nt = 0; nt < 4; ++nt) {
        bf16x8 b0 = *(bf16x8*)(KTb + SWZ(nt * 16 + fr, fk * 2));
        bf16x8 b1 = *(bf16x8*)(KTb + SWZ(nt * 16 + fr, (32 + fk) * 2));
        acc[nt] = __builtin_amdgcn_mfma_f32_16x16x32_bf16(a0, b0, acc[nt], 0, 0, 0);
        acc[nt] = __builtin_amdgcn_mfma_f32_16x16x32_bf16(a1, b1, acc[nt], 0, 0, 0);
    }

    unsigned short* dst = ckv_b + ((size_t)(h * NCHUNK + c) << 12);
#pragma unroll
    for (int nt = 0; nt < 4; ++nt) {
        const int dd = nt * 16 + fr;
#pragma unroll
        for (int r = 0; r < 4; ++r)
            dst[(er + r) * 64 + dd] = f2bf(acc[nt][r]);
    }
    if (lane < 16)
        cksc[(size_t)(h * NCHUNK + c) * HD + w * 16 + lane] = ka[0];
}

// ---------------------------------------------------------------------------
// prefix: exclusive scan over chunks. All 32 chunk values loaded upfront.
// ---------------------------------------------------------------------------
__global__ __launch_bounds__(256) void prefix_kernel(const unsigned short* __restrict__ ckv_b,
                                                     const float* __restrict__ cksc,
                                                     unsigned short* __restrict__ ckvT_b,
                                                     float* __restrict__ cks) {
    const int h = blockIdx.x;
    const int g = blockIdx.y;
    const int tid = threadIdx.x;
    const int fo = g * 512 + tid * 2;
    const size_t base = ((size_t)(h * NCHUNK)) << 12;
    unsigned int vals[NCHUNK];
#pragma unroll
    for (int c = 0; c < NCHUNK; ++c)
        vals[c] = *(const unsigned int*)&ckv_b[base + ((size_t)c << 12) + fo];
    float rx = 0.f, ry = 0.f;
#pragma unroll
    for (int c = 0; c < NCHUNK; ++c) {
        *(unsigned int*)&ckvT_b[base + ((size_t)c << 12) + fo] =
            ((unsigned int)f2bf(ry) << 16) | (unsigned int)f2bf(rx);
        rx += bf2f((unsigned short)(vals[c] & 0xFFFF));
        ry += bf2f((unsigned short)(vals[c] >> 16));
    }
    if (g == 0 && tid < 64) {
        float kv[NCHUNK];
#pragma unroll
        for (int c = 0; c < NCHUNK; ++c)
            kv[c] = cksc[(size_t)(h * NCHUNK + c) * HD + tid];
        float rk = 0.f;
#pragma unroll
        for (int c = 0; c < NCHUNK; ++c) {
            cks[(size_t)(h * NCHUNK + c) * HD + tid] = rk;
            rk += kv[c];
        }
    }
}

// ---------------------------------------------------------------------------
// Fused output kernel, 8 waves (512 threads) per 64-row tile: doubles TLP
// without duplicating staging. QK: wave (s-tile=w>>1, t-half=w&1);
// PV: wave (s-tile=w>>1, e-half=w&1). M fragments direct from L2.
// ---------------------------------------------------------------------------
__global__ __launch_bounds__(512) void fused_out_kernel(const unsigned short* __restrict__ qb,
                                                        const unsigned short* __restrict__ kb,
                                                        const unsigned short* __restrict__ vb,
                                                        const unsigned short* __restrict__ ckvT_b,
                                                        const float* __restrict__ cks,
                                                        const unsigned short* __restrict__ mbT,
                                                        const float* __restrict__ rel,
                                                        const float* __restrict__ relpart,
                                                        const float* __restrict__ gate,
                                                        unsigned short* __restrict__ cb) {
    const int h = blockIdx.x;
    const int c = blockIdx.y;
    const int s0 = c * CLEN;
    __shared__ unsigned short Qs[4096], Ks[4096], VsT[4096], KVsT[4096], Ps[4096];
    __shared__ float kp_lds[64];
    __shared__ float den_qkp[64];
    __shared__ float den_qk[2][64];
    __shared__ float c_lds[4][64];
    char* Qb  = (char*)Qs;
    char* Kb  = (char*)Ks;
    char* Vb  = (char*)VsT;
    char* KVb = (char*)KVsT;
    char* Pb  = (char*)Ps;
    const int tid = threadIdx.x;
    const int lane = tid & 63;
    const int w = tid >> 6;            // 0..7

    // --- stage Q, K (row-major), V (transposed), KVpre^T (one pass) ---
    const unsigned short* kvsrc = ckvT_b + ((size_t)(h * NCHUNK + c) << 12);
    {
        const int idx = tid * 8;
        const int r = idx >> 6, cc = idx & 63;
        const size_t gidx = (size_t)(s0 + r) * H_DIM + h * HD + cc;
        u16x8 q8 = *(const u16x8*)&qb[gidx];
        u16x8 k8 = *(const u16x8*)&kb[gidx];
        u16x8 v8 = *(const u16x8*)&vb[gidx];
        *(u16x8*)(Qb + SWZ(r, cc * 2)) = q8;
        *(u16x8*)(Kb + SWZ(r, cc * 2)) = k8;
#pragma unroll
        for (int j = 0; j < 8; ++j)
            *(unsigned short*)(Vb + SWZ(cc + j, r * 2)) = (unsigned short)v8[j];
        *(u16x8*)(KVb + SWZ(r, cc * 2)) = *(const u16x8*)&kvsrc[idx];
    }
    if (tid < 64) kp_lds[tid] = cks[(size_t)(h * NCHUNK + c) * HD + tid];
    if (tid >= 256) {
        // inline softmax weights over memories (from 4-segment partials)
        const int m = (tid - 256) >> 6, si = tid & 63;
        float v[NMEM], mx = -1e30f;
#pragma unroll
        for (int mm = 0; mm < NMEM; ++mm) {
            const float* rp = &relpart[(mm * NHEAD + h) * 4];
            v[mm] = (rp[0] + rp[1] + rp[2] + rp[3]) * (1.f / (float)S_LEN);
            mx = fmaxf(mx, v[mm]);
        }
        float sum = 0.f;
#pragma unroll
        for (int mm = 0; mm < NMEM; ++mm) { v[mm] = __expf(v[mm] - mx); sum += v[mm]; }
        const float wgt = v[m] / sum;
        c_lds[m][si] = wgt / fmaxf(rel[(size_t)(m * NHEAD + h) * S_LEN + s0 + si], EPS_C);
    }
    __syncthreads();

    // --- den_qkp[s] = q[s]·kpre (threads 0..255) ---
    if (tid < 256) {
        const int s = tid >> 2, part = tid & 3;
        bf16x8 q0 = *(bf16x8*)(Qb + SWZ(s, (part * 16) * 2));
        bf16x8 q1 = *(bf16x8*)(Qb + SWZ(s, (part * 16 + 8) * 2));
        float acc = 0.f;
#pragma unroll
        for (int jj = 0; jj < 8; ++jj) {
            acc = fmaf(bf2f((unsigned short)q0[jj]), kp_lds[part * 16 + jj], acc);
            acc = fmaf(bf2f((unsigned short)q1[jj]), kp_lds[part * 16 + 8 + jj], acc);
        }
        acc += __shfl_xor(acc, 1);
        acc += __shfl_xor(acc, 2);
        if (part == 0) den_qkp[s] = acc;
    }

    // --- QK^T: wave (si = w>>1, th = w&1 -> t cols th*32..+32) ---
    const int si = w >> 1;
    const int th = w & 1;
    const int sb = si * 16;
    const int fr = lane & 15;
    const int fk = (lane >> 4) * 8;
    bf16x8 aq0 = *(bf16x8*)(Qb + SWZ(sb + fr, fk * 2));
    bf16x8 aq1 = *(bf16x8*)(Qb + SWZ(sb + fr, (32 + fk) * 2));
    f32x4 aqk[2] = {};
#pragma unroll
    for (int nt = 0; nt < 2; ++nt) {
        const int trow = th * 32 + nt * 16 + fr;
        bf16x8 bk0 = *(bf16x8*)(Kb + SWZ(trow, fk * 2));
        bf16x8 bk1 = *(bf16x8*)(Kb + SWZ(trow, (32 + fk) * 2));
        aqk[nt] = __builtin_amdgcn_mfma_f32_16x16x32_bf16(aq0, bk0, aqk[nt], 0, 0, 0);
        aqk[nt] = __builtin_amdgcn_mfma_f32_16x16x32_bf16(aq1, bk1, aqk[nt], 0, 0, 0);
    }
    // mask (t<=s), write P bf16, accumulate row sums (partial per t-half)
    float rs[4] = {0.f, 0.f, 0.f, 0.f};
    const int srow0 = sb + (lane >> 4) * 4;
#pragma unroll
    for (int nt = 0; nt < 2; ++nt) {
        const int t = th * 32 + nt * 16 + fr;
#pragma unroll
        for (int r = 0; r < 4; ++r) {
            const int s = srow0 + r;
            const float pv = (t <= s) ? aqk[nt][r] : 0.f;
            rs[r] += pv;
            *(unsigned short*)(Pb + SWZ(s, t * 2)) = f2bf(pv);
        }
    }
#pragma unroll
    for (int m = 1; m < 16; m <<= 1) {
        rs[0] += __shfl_xor(rs[0], m);
        rs[1] += __shfl_xor(rs[1], m);
        rs[2] += __shfl_xor(rs[2], m);
        rs[3] += __shfl_xor(rs[3], m);
    }
    if (fr == 0) {
#pragma unroll
        for (int r = 0; r < 4; ++r) den_qk[th][srow0 + r] = rs[r];
    }
    __syncthreads();

    // --- PV + QKVpre + mem: wave (si, eh = w&1 -> e cols eh*32..+32) ---
    const int eh = th;
    const float g = 1.f / (1.f + __expf(-gate[h]));
    const float gl = 1.f - g;
    const unsigned short* mb0 = mbT + (size_t)(0 * NHEAD + h) * 4096;
    const unsigned short* mb1 = mbT + (size_t)(1 * NHEAD + h) * 4096;
    const unsigned short* mb2 = mbT + (size_t)(2 * NHEAD + h) * 4096;
    const unsigned short* mb3 = mbT + (size_t)(3 * NHEAD + h) * 4096;
    bf16x8 ap0 = *(bf16x8*)(Pb + SWZ(sb + fr, fk * 2));
    bf16x8 ap1 = *(bf16x8*)(Pb + SWZ(sb + fr, (32 + fk) * 2));
#pragma unroll
    for (int nt = 0; nt < 2; ++nt) {
        const int er = eh * 32 + nt * 16 + fr;
        f32x4 lacc = {};
        bf16x8 bv0 = *(bf16x8*)(Vb + SWZ(er, fk * 2));
        bf16x8 bv1 = *(bf16x8*)(Vb + SWZ(er, (32 + fk) * 2));
        lacc = __builtin_amdgcn_mfma_f32_16x16x32_bf16(ap0, bv0, lacc, 0, 0, 0);
        lacc = __builtin_amdgcn_mfma_f32_16x16x32_bf16(ap1, bv1, lacc, 0, 0, 0);
        bf16x8 bkv0 = *(bf16x8*)(KVb + SWZ(er, fk * 2));
        bf16x8 bkv1 = *(bf16x8*)(KVb + SWZ(er, (32 + fk) * 2));
        lacc = __builtin_amdgcn_mfma_f32_16x16x32_bf16(aq0, bkv0, lacc, 0, 0, 0);
        lacc = __builtin_amdgcn_mfma_f32_16x16x32_bf16(aq1, bkv1, lacc, 0, 0, 0);

        const int mrow = er * 64;
        f32x4 macc = {};
        {
            f32x4 mm = {};
            mm = __builtin_amdgcn_mfma_f32_16x16x32_bf16(aq0, *(const bf16x8*)&mb0[mrow + fk], mm, 0, 0, 0);
            mm = __builtin_amdgcn_mfma_f32_16x16x32_bf16(aq1, *(const bf16x8*)&mb0[mrow + 32 + fk], mm, 0, 0, 0);
#pragma unroll
            for (int r = 0; r < 4; ++r) macc[r] = fmaf(c_lds[0][srow0 + r], mm[r], macc[r]);
        }
        {
            f32x4 mm = {};
            mm = __builtin_amdgcn_mfma_f32_16x16x32_bf16(aq0, *(const bf16x8*)&mb1[mrow + fk], mm, 0, 0, 0);
            mm = __builtin_amdgcn_mfma_f32_16x16x32_bf16(aq1, *(const bf16x8*)&mb1[mrow + 32 + fk], mm, 0, 0, 0);
#pragma unroll
            for (int r = 0; r < 4; ++r) macc[r] = fmaf(c_lds[1][srow0 + r], mm[r], macc[r]);
        }
        {
            f32x4 mm = {};
            mm = __builtin_amdgcn_mfma_f32_16x16x32_bf16(aq0, *(const bf16x8*)&mb2[mrow + fk], mm, 0, 0, 0);
            mm = __builtin_amdgcn_mfma_f32_16x16x32_bf16(aq1, *(const bf16x8*)&mb2[mrow + 32 + fk], mm, 0, 0, 0);
#pragma unroll
            for (int r = 0; r < 4; ++r) macc[r] = fmaf(c_lds[2][srow0 + r], mm[r], macc[r]);
        }
        {
            f32x4 mm = {};
            mm = __builtin_amdgcn_mfma_f32_16x16x32_bf16(aq0, *(const bf16x8*)&mb3[mrow + fk], mm, 0, 0, 0);
            mm = __builtin_amdgcn_mfma_f32_16x16x32_bf16(aq1, *(const bf16x8*)&mb3[mrow + 32 + fk], mm, 0, 0, 0);
#pragma unroll
            for (int r = 0; r < 4; ++r) macc[r] = fmaf(c_lds[3][srow0 + r], mm[r], macc[r]);
        }

        const int e = eh * 32 + nt * 16 + fr;
#pragma unroll
        for (int r = 0; r < 4; ++r) {
            const int s = srow0 + r;
            const float den = fmaxf(den_qkp[s] + den_qk[0][s] + den_qk[1][s], EPS_C);
            const float val = g * macc[r] + gl * lacc[r] / den;
            cb[(size_t)(s0 + s) * H_DIM + h * HD + e] = f2bf(val);
        }
    }
}

extern "C" void kernel_launch(void* const* d_in, const int* in_sizes, int n_in,
                              void* d_out, int out_size, void* d_ws, size_t ws_size,
                              hipStream_t stream) {
    const float* hidden   = (const float*)d_in[0];
    const float* w_q      = (const float*)d_in[1];
    const float* w_k      = (const float*)d_in[2];
    const float* w_v      = (const float*)d_in[3];
    const float* w_o      = (const float*)d_in[4];
    const float* gate     = (const float*)d_in[5];
    const float* memories = (const float*)d_in[6];
    const float* memnorms = (const float*)d_in[7];
    float* out = (float*)d_out;

    float* ws = (float*)d_ws;
    size_t off = 0;
    float* rel     = ws + off; off += (size_t)NMEM * NHEAD * S_LEN;
    float* relpart = ws + off; off += 256;
    float* cks     = ws + off; off += (size_t)NHEAD * NCHUNK * HD;
    float* cksc    = ws + off; off += (size_t)NHEAD * NCHUNK * HD;
    unsigned short* ckv_b  = (unsigned short*)(ws + off); off += (size_t)NHEAD * NCHUNK * HD * HD / 2;
    unsigned short* ckvT_b = (unsigned short*)(ws + off); off += (size_t)NHEAD * NCHUNK * HD * HD / 2;
    unsigned short* hb  = (unsigned short*)(ws + off); off += (size_t)S_LEN * H_DIM / 2;
    unsigned short* wb  = (unsigned short*)(ws + off); off += (size_t)3 * H_DIM * H_DIM / 2;
    unsigned short* wob = (unsigned short*)(ws + off); off += (size_t)H_DIM * H_DIM / 2;
    unsigned short* qb  = (unsigned short*)(ws + off); off += (size_t)S_LEN * H_DIM / 2;
    unsigned short* kb  = (unsigned short*)(ws + off); off += (size_t)S_LEN * H_DIM / 2;
    unsigned short* vb  = (unsigned short*)(ws + off); off += (size_t)S_LEN * H_DIM / 2;
    unsigned short* cb  = (unsigned short*)(ws + off); off += (size_t)S_LEN * H_DIM / 2;
    unsigned short* mbT = (unsigned short*)(ws + off); off += (size_t)NMEM * NHEAD * HD * HD / 2;

    // 1. conversions + memory transpose
    prep_kernel<<<3136, 256, 0, stream>>>(hidden, w_q, w_k, w_v, w_o, memories,
                                          hb, wb, wob, mbT);
    // 2. fused QKV projection (BM=64/BN=128/BK=64 dbuf, 768 blocks = 3/CU)
    gemm_mfma_kernel<1, 128><<<768, 256, 0, stream>>>(
        hb, wb, nullptr, qb, kb, vb, H_DIM, 3);
    // 3. per-chunk KV state + relevance (merged, 16x36 blocks)
    chunkkv_rel_kernel<<<dim3(NHEAD, 36), 256, 0, stream>>>(
        kb, vb, qb, memnorms, ckv_b, cksc, rel, relpart);
    // 4. exclusive prefix scan (upfront-load register scan, 128 blocks)
    prefix_kernel<<<dim3(NHEAD, 8), 256, 0, stream>>>(ckv_b, cksc, ckvT_b, cks);
    // 5. fused memory + local output (64-row tiles, 8 waves/block)
    fused_out_kernel<<<dim3(NHEAD, NCHUNK), 512, 0, stream>>>(
        qb, kb, vb, ckvT_b, cks, mbT, rel, relpart, gate, cb);
    // 6. output projection (BM=64/BN=64, 512 blocks = 2/CU)
    gemm_mfma_kernel<0, 64><<<512, 256, 0, stream>>>(
        cb, wob, out, nullptr, nullptr, nullptr, H_DIM, 2);
}

// Round 16
// 73.647 us; speedup vs baseline: 1.0619x; 1.0115x over previous
//
#include <hip/hip_runtime.h>
#include <hip/hip_bf16.h>
#include <math.h>

#define S_LEN 2048
#define H_DIM 1024
#define NHEAD 16
#define HD 64
#define NMEM 4
#define NCHUNK 32
#define CLEN 64
#define EPS_C 1e-6f

typedef __attribute__((ext_vector_type(8))) short bf16x8;
typedef __attribute__((ext_vector_type(4))) float f32x4;
typedef __attribute__((ext_vector_type(8))) unsigned short u16x8;
typedef __attribute__((ext_vector_type(4))) unsigned short u16x4;

__device__ __forceinline__ unsigned short f2bf(float f) {
    unsigned int u = __float_as_uint(f);
    u += 0x7FFFu + ((u >> 16) & 1u);   // round-to-nearest-even
    return (unsigned short)(u >> 16);
}
__device__ __forceinline__ float bf2f(unsigned short u) {
    return __uint_as_float((unsigned int)u << 16);
}

// swizzle for 64-col bf16 tiles, 128B rows (G4: byte ^= (row&7)<<4)
#define SWZ(row, colbyte) ((row) * 128 + ((colbyte) ^ (((row) & 7) << 4)))

// ---------------------------------------------------------------------------
// prep: all f32->bf16 conversions + memories transpose, one launch.
// ---------------------------------------------------------------------------
__global__ __launch_bounds__(256) void prep_kernel(const float* __restrict__ hidden,
                                                   const float* __restrict__ w_q,
                                                   const float* __restrict__ w_k,
                                                   const float* __restrict__ w_v,
                                                   const float* __restrict__ w_o,
                                                   const float* __restrict__ memories,
                                                   unsigned short* __restrict__ hb,
                                                   unsigned short* __restrict__ wb,
                                                   unsigned short* __restrict__ wob,
                                                   unsigned short* __restrict__ mbT) {
    const int b = blockIdx.x;
    const int tid = threadIdx.x;
    __shared__ float t[64][65];
    if (b < 3072) {
        const float* src;
        unsigned short* dst;
        int base;
        if (b < 1024)      { src = hidden; dst = hb;            base = b; }
        else if (b < 1536) { src = w_q;    dst = wb;            base = b - 1024; }
        else if (b < 2048) { src = w_k;    dst = wb + 1048576;  base = b - 1536; }
        else if (b < 2560) { src = w_v;    dst = wb + 2097152;  base = b - 2048; }
        else               { src = w_o;    dst = wob;           base = b - 2560; }
        const int i = base * 2048 + tid * 8;
        float4 a = *(const float4*)(src + i);
        float4 c = *(const float4*)(src + i + 4);
        u16x8 o;
        o[0] = f2bf(a.x); o[1] = f2bf(a.y); o[2] = f2bf(a.z); o[3] = f2bf(a.w);
        o[4] = f2bf(c.x); o[5] = f2bf(c.y); o[6] = f2bf(c.z); o[7] = f2bf(c.w);
        *(u16x8*)(dst + i) = o;
    } else {
        const int mh = b - 3072;
        const float* src = memories + (size_t)mh * 4096;
#pragma unroll
        for (int j = 0; j < 4; ++j) {
            const int idx = j * 1024 + tid * 4;
            *(float4*)&t[idx >> 6][idx & 63] = *(const float4*)&src[idx];
        }
        __syncthreads();
        unsigned short* dst = mbT + (size_t)mh * 4096;
#pragma unroll
        for (int j = 0; j < 4; ++j) {
            const int idx = j * 1024 + tid * 4;
            const int e = idx >> 6, d = idx & 63;
            u16x4 o;
#pragma unroll
            for (int i = 0; i < 4; ++i) o[i] = f2bf(t[d + i][e]);
            *(u16x4*)&dst[idx] = o;
        }
    }
}

// ---------------------------------------------------------------------------
// MFMA bf16 GEMM, BM x BN template tiles, BK=64 (two 32-planes), double-
// buffered LDS, prefetch-before-compute (one barrier per K-tile).
// 4 waves in 2x2: wave tile (BM/2) x (BN/2). XCD-chunked 1D grid.
// MODE 0: f32 out (no act). MODE 1: qkv, bf16 out, per-ni seg dst + elu1.
// ---------------------------------------------------------------------------
template <int MODE, int BM, int BN, int NCOLS>
__global__ __launch_bounds__(256) void gemm_mfma_kernel(const unsigned short* __restrict__ A,
                                                        const unsigned short* __restrict__ B,
                                                        float* __restrict__ f32out,
                                                        unsigned short* __restrict__ b0,
                                                        unsigned short* __restrict__ b1,
                                                        unsigned short* __restrict__ b2,
                                                        int K) {
    constexpr int NMI = BM / 32;        // A row-frags per wave
    constexpr int NNI = BN / 32;        // B col-frags per wave
    constexpr int MBLK = 2048 / BM;
    constexpr int NBLK = NCOLS / BN;
    constexpr int PERX = NBLK / 8;
    __shared__ unsigned short Als[2][2][BM][32];    // buf, kplane, row, k
    __shared__ unsigned short Bls[2][2][BN][32];
    const int tid  = threadIdx.x;
    const int lane = tid & 63;
    const int wv   = tid >> 6;
    const int wr   = wv >> 1;
    const int wc   = wv & 1;
    const int d    = blockIdx.x;
    const int xcd  = d & 7;
    const int j    = d >> 3;
    const int y    = xcd * PERX + j / MBLK;
    const int x    = j % MBLK;
    const int bm   = x * BM;
    const int bn   = y * BN;

    const int lrow = lane >> 2;          // 0..15 within a 16-row staging unit
    const int skc  = (lane & 3) << 3;

    const int frow = lane & 15;
    const int fkof = (lane >> 4) << 3;

    f32x4 acc[NMI][NNI] = {};

    auto stage = [&](int buf, int t) {
        const size_t ko = (size_t)t * 64;
#pragma unroll
        for (int pl = 0; pl < 2; ++pl) {
#pragma unroll
            for (int i = wv; i < BM / 16; i += 4)
                __builtin_amdgcn_global_load_lds(
                    (const __attribute__((address_space(1))) void*)
                        (A + (size_t)(bm + i * 16 + lrow) * K + skc + ko + pl * 32),
                    (__attribute__((address_space(3))) void*)&Als[buf][pl][i * 16][0], 16, 0, 0);
#pragma unroll
            for (int i = wv; i < BN / 16; i += 4)
                __builtin_amdgcn_global_load_lds(
                    (const __attribute__((address_space(1))) void*)
                        (B + (size_t)(bn + i * 16 + lrow) * K + skc + ko + pl * 32),
                    (__attribute__((address_space(3))) void*)&Bls[buf][pl][i * 16][0], 16, 0, 0);
        }
    };

    const int NT = K >> 6;   // 16 for K=1024
    stage(0, 0);
    __syncthreads();
    int cur = 0;
    for (int t = 0; t < NT; ++t) {
        if (t + 1 < NT) stage(cur ^ 1, t + 1);   // prefetch next tile (overlaps compute)
        bf16x8 af[2][NMI], bf[2][NNI];
#pragma unroll
        for (int pl = 0; pl < 2; ++pl) {
#pragma unroll
            for (int mi = 0; mi < NMI; ++mi)
                af[pl][mi] = *(const bf16x8*)&Als[cur][pl][wr * (BM / 2) + mi * 16 + frow][fkof];
#pragma unroll
            for (int ni = 0; ni < NNI; ++ni)
                bf[pl][ni] = *(const bf16x8*)&Bls[cur][pl][wc * (BN / 2) + ni * 16 + frow][fkof];
        }
#pragma unroll
        for (int pl = 0; pl < 2; ++pl)
#pragma unroll
            for (int mi = 0; mi < NMI; ++mi)
#pragma unroll
                for (int ni = 0; ni < NNI; ++ni)
                    acc[mi][ni] = __builtin_amdgcn_mfma_f32_16x16x32_bf16(af[pl][mi], bf[pl][ni], acc[mi][ni], 0, 0, 0);
        __syncthreads();   // drains prefetch vmcnt + protects buf reuse
        cur ^= 1;
    }

    const int crow = (lane >> 4) << 2;
    const int ccol = lane & 15;
#pragma unroll
    for (int mi = 0; mi < NMI; ++mi) {
#pragma unroll
        for (int ni = 0; ni < NNI; ++ni) {
            // per-ni segment selection (16-col fragment never spans a 1024 boundary)
            const int segBase = bn + wc * (BN / 2) + ni * 16;
            unsigned short* bdst = b0;
            bool act = true;
            if (MODE == 1) {
                const int seg = segBase >> 10;
                bdst = (seg == 0) ? b0 : ((seg == 1) ? b1 : b2);
                act = (seg < 2);
            }
            const int colOut = (MODE == 1 ? (segBase & 1023) : segBase) + ccol;
#pragma unroll
            for (int r = 0; r < 4; ++r) {
                const int row = bm + wr * (BM / 2) + mi * 16 + crow + r;
                float xv = acc[mi][ni][r];
                if (MODE == 0) {
                    f32out[(size_t)row * 1024 + colOut] = xv;
                } else {
                    if (act) xv = (xv > 0.f) ? (xv + 1.f) : __expf(xv);
                    bdst[(size_t)row * 1024 + colOut] = f2bf(xv);
                }
            }
        }
    }
}

// ---------------------------------------------------------------------------
// chunkkv + rel merged kernel. grid (NHEAD, 36):
//   y <  32: chunkkv for chunk y  -> ckv_b (bf16), cksc
//   y >= 32: rel for s-segment (y-32)*512 -> rel, relpart
// ---------------------------------------------------------------------------
__global__ __launch_bounds__(256) void chunkkv_rel_kernel(const unsigned short* __restrict__ kb,
                                                          const unsigned short* __restrict__ vb,
                                                          const unsigned short* __restrict__ qb,
                                                          const float* __restrict__ norms,
                                                          unsigned short* __restrict__ ckv_b,
                                                          float* __restrict__ cksc,
                                                          float* __restrict__ rel,
                                                          float* __restrict__ relpart) {
    const int h = blockIdx.x;
    const int tid = threadIdx.x;
    __shared__ unsigned short KT[4096], VT[4096];
    __shared__ float red[256];

    if (blockIdx.y >= 32) {
        // ---------------- rel path ----------------
        const int seg = blockIdx.y - 32;
        float* nl = (float*)KT;          // reuse LDS: 4*64 floats
        {
            const int m = tid >> 6, dd = tid & 63;
            nl[m * 64 + dd] = norms[(size_t)(m * NHEAD + h) * HD + dd];
        }
        __syncthreads();
        float sums[4] = {0.f, 0.f, 0.f, 0.f};
#pragma unroll
        for (int it = 0; it < 2; ++it) {
            const int s = seg * 512 + it * 256 + tid;
            const unsigned short* row = qb + (size_t)s * H_DIM + h * HD;
            float dot[4] = {0.f, 0.f, 0.f, 0.f};
#pragma unroll
            for (int d0 = 0; d0 < 64; d0 += 8) {
                u16x8 v = *(const u16x8*)(row + d0);
#pragma unroll
                for (int i = 0; i < 8; ++i) {
                    const float qv = bf2f(v[i]);
                    dot[0] = fmaf(qv, nl[0 * 64 + d0 + i], dot[0]);
                    dot[1] = fmaf(qv, nl[1 * 64 + d0 + i], dot[1]);
                    dot[2] = fmaf(qv, nl[2 * 64 + d0 + i], dot[2]);
                    dot[3] = fmaf(qv, nl[3 * 64 + d0 + i], dot[3]);
                }
            }
#pragma unroll
            for (int m = 0; m < NMEM; ++m) {
                rel[(size_t)(m * NHEAD + h) * S_LEN + s] = dot[m];
                sums[m] += dot[m];
            }
        }
#pragma unroll
        for (int m = 0; m < NMEM; ++m) {
            red[tid] = sums[m];
            __syncthreads();
            for (int o = 128; o > 0; o >>= 1) {
                if (tid < o) red[tid] += red[tid + o];
                __syncthreads();
            }
            if (tid == 0) relpart[(m * NHEAD + h) * 4 + seg] = red[0];
            __syncthreads();
        }
        return;
    }

    // ---------------- chunkkv path ----------------
    const int c = blockIdx.y;
    const int s0 = c * CLEN;
    char* KTb = (char*)KT;
    char* VTb = (char*)VT;
    const int lane = tid & 63;
    const int w = tid >> 6;
    const int fr = lane & 15;
    const int fk = (lane >> 4) * 8;
    const int er = w * 16 + (lane >> 4) * 4;

    const int idx0 = tid * 8, idx1 = 2048 + tid * 8;
    const int r0 = idx0 >> 6, c0 = idx0 & 63;
    const int r1 = idx1 >> 6, c1 = idx1 & 63;

    u16x8 k0 = *(const u16x8*)&kb[(size_t)(s0 + r0) * H_DIM + h * HD + c0];
    u16x8 k1 = *(const u16x8*)&kb[(size_t)(s0 + r1) * H_DIM + h * HD + c1];
    u16x8 v0 = *(const u16x8*)&vb[(size_t)(s0 + r0) * H_DIM + h * HD + c0];
    u16x8 v1 = *(const u16x8*)&vb[(size_t)(s0 + r1) * H_DIM + h * HD + c1];
#pragma unroll
    for (int j = 0; j < 8; ++j) {
        *(unsigned short*)(KTb + SWZ(c0 + j, r0 * 2)) = (unsigned short)k0[j];
        *(unsigned short*)(KTb + SWZ(c1 + j, r1 * 2)) = (unsigned short)k1[j];
        *(unsigned short*)(VTb + SWZ(c0 + j, r0 * 2)) = (unsigned short)v0[j];
        *(unsigned short*)(VTb + SWZ(c1 + j, r1 * 2)) = (unsigned short)v1[j];
    }
    __syncthreads();

    bf16x8 a0 = *(bf16x8*)(VTb + SWZ(w * 16 + fr, fk * 2));
    bf16x8 a1 = *(bf16x8*)(VTb + SWZ(w * 16 + fr, (32 + fk) * 2));
    f32x4 acc[4] = {};
    bf16x8 ones;
#pragma unroll
    for (int i = 0; i < 8; ++i) ones[i] = (short)0x3F80;
    bf16x8 bw0 = *(bf16x8*)(KTb + SWZ(w * 16 + fr, fk * 2));
    bf16x8 bw1 = *(bf16x8*)(KTb + SWZ(w * 16 + fr, (32 + fk) * 2));
    f32x4 ka = {};
    ka = __builtin_amdgcn_mfma_f32_16x16x32_bf16(ones, bw0, ka, 0, 0, 0);
    ka = __builtin_amdgcn_mfma_f32_16x16x32_bf16(ones, bw1, ka, 0, 0, 0);
#pragma unroll
    for (int nt = 0; nt < 4; ++nt) {
        bf16x8 b0 = *(bf16x8*)(KTb + SWZ(nt * 16 + fr, fk * 2));
        bf16x8 b1 = *(bf16x8*)(KTb + SWZ(nt * 16 + fr, (32 + fk) * 2));
        acc[nt] = __builtin_amdgcn_mfma_f32_16x16x32_bf16(a0, b0, acc[nt], 0, 0, 0);
        acc[nt] = __builtin_amdgcn_mfma_f32_16x16x32_bf16(a1, b1, acc[nt], 0, 0, 0);
    }

    unsigned short* dst = ckv_b + ((size_t)(h * NCHUNK + c) << 12);
#pragma unroll
    for (int nt = 0; nt < 4; ++nt) {
        const int dd = nt * 16 + fr;
#pragma unroll
        for (int r = 0; r < 4; ++r)
            dst[(er + r) * 64 + dd] = f2bf(acc[nt][r]);
    }
    if (lane < 16)
        cksc[(size_t)(h * NCHUNK + c) * HD + w * 16 + lane] = ka[0];
}

// ---------------------------------------------------------------------------
// prefix: exclusive scan over chunks. All 32 chunk values loaded upfront.
// ---------------------------------------------------------------------------
__global__ __launch_bounds__(256) void prefix_kernel(const unsigned short* __restrict__ ckv_b,
                                                     const float* __restrict__ cksc,
                                                     unsigned short* __restrict__ ckvT_b,
                                                     float* __restrict__ cks) {
    const int h = blockIdx.x;
    const int g = blockIdx.y;
    const int tid = threadIdx.x;
    const int fo = g * 512 + tid * 2;
    const size_t base = ((size_t)(h * NCHUNK)) << 12;
    unsigned int vals[NCHUNK];
#pragma unroll
    for (int c = 0; c < NCHUNK; ++c)
        vals[c] = *(const unsigned int*)&ckv_b[base + ((size_t)c << 12) + fo];
    float rx = 0.f, ry = 0.f;
#pragma unroll
    for (int c = 0; c < NCHUNK; ++c) {
        *(unsigned int*)&ckvT_b[base + ((size_t)c << 12) + fo] =
            ((unsigned int)f2bf(ry) << 16) | (unsigned int)f2bf(rx);
        rx += bf2f((unsigned short)(vals[c] & 0xFFFF));
        ry += bf2f((unsigned short)(vals[c] >> 16));
    }
    if (g == 0 && tid < 64) {
        float kv[NCHUNK];
#pragma unroll
        for (int c = 0; c < NCHUNK; ++c)
            kv[c] = cksc[(size_t)(h * NCHUNK + c) * HD + tid];
        float rk = 0.f;
#pragma unroll
        for (int c = 0; c < NCHUNK; ++c) {
            cks[(size_t)(h * NCHUNK + c) * HD + tid] = rk;
            rk += kv[c];
        }
    }
}

// ---------------------------------------------------------------------------
// Fused output kernel, 8 waves (512 threads) per 64-row tile.
// QK: wave (s-tile=w>>1, t-half=w&1); PV: wave (s-tile, e-half).
// M fragments direct from L2.
// ---------------------------------------------------------------------------
__global__ __launch_bounds__(512) void fused_out_kernel(const unsigned short* __restrict__ qb,
                                                        const unsigned short* __restrict__ kb,
                                                        const unsigned short* __restrict__ vb,
                                                        const unsigned short* __restrict__ ckvT_b,
                                                        const float* __restrict__ cks,
                                                        const unsigned short* __restrict__ mbT,
                                                        const float* __restrict__ rel,
                                                        const float* __restrict__ relpart,
                                                        const float* __restrict__ gate,
                                                        unsigned short* __restrict__ cb) {
    const int h = blockIdx.x;
    const int c = blockIdx.y;
    const int s0 = c * CLEN;
    __shared__ unsigned short Qs[4096], Ks[4096], VsT[4096], KVsT[4096], Ps[4096];
    __shared__ float kp_lds[64];
    __shared__ float den_qkp[64];
    __shared__ float den_qk[2][64];
    __shared__ float c_lds[4][64];
    char* Qb  = (char*)Qs;
    char* Kb  = (char*)Ks;
    char* Vb  = (char*)VsT;
    char* KVb = (char*)KVsT;
    char* Pb  = (char*)Ps;
    const int tid = threadIdx.x;
    const int lane = tid & 63;
    const int w = tid >> 6;            // 0..7

    // --- stage Q, K (row-major), V (transposed), KVpre^T (one pass) ---
    const unsigned short* kvsrc = ckvT_b + ((size_t)(h * NCHUNK + c) << 12);
    {
        const int idx = tid * 8;
        const int r = idx >> 6, cc = idx & 63;
        const size_t gidx = (size_t)(s0 + r) * H_DIM + h * HD + cc;
        u16x8 q8 = *(const u16x8*)&qb[gidx];
        u16x8 k8 = *(const u16x8*)&kb[gidx];
        u16x8 v8 = *(const u16x8*)&vb[gidx];
        *(u16x8*)(Qb + SWZ(r, cc * 2)) = q8;
        *(u16x8*)(Kb + SWZ(r, cc * 2)) = k8;
#pragma unroll
        for (int j = 0; j < 8; ++j)
            *(unsigned short*)(Vb + SWZ(cc + j, r * 2)) = (unsigned short)v8[j];
        *(u16x8*)(KVb + SWZ(r, cc * 2)) = *(const u16x8*)&kvsrc[idx];
    }
    if (tid < 64) kp_lds[tid] = cks[(size_t)(h * NCHUNK + c) * HD + tid];
    if (tid >= 256) {
        // inline softmax weights over memories (from 4-segment partials)
        const int m = (tid - 256) >> 6, si = tid & 63;
        float v[NMEM], mx = -1e30f;
#pragma unroll
        for (int mm = 0; mm < NMEM; ++mm) {
            const float* rp = &relpart[(mm * NHEAD + h) * 4];
            v[mm] = (rp[0] + rp[1] + rp[2] + rp[3]) * (1.f / (float)S_LEN);
            mx = fmaxf(mx, v[mm]);
        }
        float sum = 0.f;
#pragma unroll
        for (int mm = 0; mm < NMEM; ++mm) { v[mm] = __expf(v[mm] - mx); sum += v[mm]; }
        const float wgt = v[m] / sum;
        c_lds[m][si] = wgt / fmaxf(rel[(size_t)(m * NHEAD + h) * S_LEN + s0 + si], EPS_C);
    }
    __syncthreads();

    // --- den_qkp[s] = q[s]·kpre (threads 0..255) ---
    if (tid < 256) {
        const int s = tid >> 2, part = tid & 3;
        bf16x8 q0 = *(bf16x8*)(Qb + SWZ(s, (part * 16) * 2));
        bf16x8 q1 = *(bf16x8*)(Qb + SWZ(s, (part * 16 + 8) * 2));
        float acc = 0.f;
#pragma unroll
        for (int jj = 0; jj < 8; ++jj) {
            acc = fmaf(bf2f((unsigned short)q0[jj]), kp_lds[part * 16 + jj], acc);
            acc = fmaf(bf2f((unsigned short)q1[jj]), kp_lds[part * 16 + 8 + jj], acc);
        }
        acc += __shfl_xor(acc, 1);
        acc += __shfl_xor(acc, 2);
        if (part == 0) den_qkp[s] = acc;
    }

    // --- QK^T: wave (si = w>>1, th = w&1 -> t cols th*32..+32) ---
    const int si = w >> 1;
    const int th = w & 1;
    const int sb = si * 16;
    const int fr = lane & 15;
    const int fk = (lane >> 4) * 8;
    bf16x8 aq0 = *(bf16x8*)(Qb + SWZ(sb + fr, fk * 2));
    bf16x8 aq1 = *(bf16x8*)(Qb + SWZ(sb + fr, (32 + fk) * 2));
    f32x4 aqk[2] = {};
#pragma unroll
    for (int nt = 0; nt < 2; ++nt) {
        const int trow = th * 32 + nt * 16 + fr;
        bf16x8 bk0 = *(bf16x8*)(Kb + SWZ(trow, fk * 2));
        bf16x8 bk1 = *(bf16x8*)(Kb + SWZ(trow, (32 + fk) * 2));
        aqk[nt] = __builtin_amdgcn_mfma_f32_16x16x32_bf16(aq0, bk0, aqk[nt], 0, 0, 0);
        aqk[nt] = __builtin_amdgcn_mfma_f32_16x16x32_bf16(aq1, bk1, aqk[nt], 0, 0, 0);
    }
    // mask (t<=s), write P bf16, accumulate row sums (partial per t-half)
    float rs[4] = {0.f, 0.f, 0.f, 0.f};
    const int srow0 = sb + (lane >> 4) * 4;
#pragma unroll
    for (int nt = 0; nt < 2; ++nt) {
        const int t = th * 32 + nt * 16 + fr;
#pragma unroll
        for (int r = 0; r < 4; ++r) {
            const int s = srow0 + r;
            const float pv = (t <= s) ? aqk[nt][r] : 0.f;
            rs[r] += pv;
            *(unsigned short*)(Pb + SWZ(s, t * 2)) = f2bf(pv);
        }
    }
#pragma unroll
    for (int m = 1; m < 16; m <<= 1) {
        rs[0] += __shfl_xor(rs[0], m);
        rs[1] += __shfl_xor(rs[1], m);
        rs[2] += __shfl_xor(rs[2], m);
        rs[3] += __shfl_xor(rs[3], m);
    }
    if (fr == 0) {
#pragma unroll
        for (int r = 0; r < 4; ++r) den_qk[th][srow0 + r] = rs[r];
    }
    __syncthreads();

    // --- PV + QKVpre + mem: wave (si, eh = w&1 -> e cols eh*32..+32) ---
    const int eh = th;
    const float g = 1.f / (1.f + __expf(-gate[h]));
    const float gl = 1.f - g;
    const unsigned short* mb0 = mbT + (size_t)(0 * NHEAD + h) * 4096;
    const unsigned short* mb1 = mbT + (size_t)(1 * NHEAD + h) * 4096;
    const unsigned short* mb2 = mbT + (size_t)(2 * NHEAD + h) * 4096;
    const unsigned short* mb3 = mbT + (size_t)(3 * NHEAD + h) * 4096;
    bf16x8 ap0 = *(bf16x8*)(Pb + SWZ(sb + fr, fk * 2));
    bf16x8 ap1 = *(bf16x8*)(Pb + SWZ(sb + fr, (32 + fk) * 2));
#pragma unroll
    for (int nt = 0; nt < 2; ++nt) {
        const int er = eh * 32 + nt * 16 + fr;
        f32x4 lacc = {};
        bf16x8 bv0 = *(bf16x8*)(Vb + SWZ(er, fk * 2));
        bf16x8 bv1 = *(bf16x8*)(Vb + SWZ(er, (32 + fk) * 2));
        lacc = __builtin_amdgcn_mfma_f32_16x16x32_bf16(ap0, bv0, lacc, 0, 0, 0);
        lacc = __builtin_amdgcn_mfma_f32_16x16x32_bf16(ap1, bv1, lacc, 0, 0, 0);
        bf16x8 bkv0 = *(bf16x8*)(KVb + SWZ(er, fk * 2));
        bf16x8 bkv1 = *(bf16x8*)(KVb + SWZ(er, (32 + fk) * 2));
        lacc = __builtin_amdgcn_mfma_f32_16x16x32_bf16(aq0, bkv0, lacc, 0, 0, 0);
        lacc = __builtin_amdgcn_mfma_f32_16x16x32_bf16(aq1, bkv1, lacc, 0, 0, 0);

        const int mrow = er * 64;
        f32x4 macc = {};
        {
            f32x4 mm = {};
            mm = __builtin_amdgcn_mfma_f32_16x16x32_bf16(aq0, *(const bf16x8*)&mb0[mrow + fk], mm, 0, 0, 0);
            mm = __builtin_amdgcn_mfma_f32_16x16x32_bf16(aq1, *(const bf16x8*)&mb0[mrow + 32 + fk], mm, 0, 0, 0);
#pragma unroll
            for (int r = 0; r < 4; ++r) macc[r] = fmaf(c_lds[0][srow0 + r], mm[r], macc[r]);
        }
        {
            f32x4 mm = {};
            mm = __builtin_amdgcn_mfma_f32_16x16x32_bf16(aq0, *(const bf16x8*)&mb1[mrow + fk], mm, 0, 0, 0);
            mm = __builtin_amdgcn_mfma_f32_16x16x32_bf16(aq1, *(const bf16x8*)&mb1[mrow + 32 + fk], mm, 0, 0, 0);
#pragma unroll
            for (int r = 0; r < 4; ++r) macc[r] = fmaf(c_lds[1][srow0 + r], mm[r], macc[r]);
        }
        {
            f32x4 mm = {};
            mm = __builtin_amdgcn_mfma_f32_16x16x32_bf16(aq0, *(const bf16x8*)&mb2[mrow + fk], mm, 0, 0, 0);
            mm = __builtin_amdgcn_mfma_f32_16x16x32_bf16(aq1, *(const bf16x8*)&mb2[mrow + 32 + fk], mm, 0, 0, 0);
#pragma unroll
            for (int r = 0; r < 4; ++r) macc[r] = fmaf(c_lds[2][srow0 + r], mm[r], macc[r]);
        }
        {
            f32x4 mm = {};
            mm = __builtin_amdgcn_mfma_f32_16x16x32_bf16(aq0, *(const bf16x8*)&mb3[mrow + fk], mm, 0, 0, 0);
            mm = __builtin_amdgcn_mfma_f32_16x16x32_bf16(aq1, *(const bf16x8*)&mb3[mrow + 32 + fk], mm, 0, 0, 0);
#pragma unroll
            for (int r = 0; r < 4; ++r) macc[r] = fmaf(c_lds[3][srow0 + r], mm[r], macc[r]);
        }

        const int e = eh * 32 + nt * 16 + fr;
#pragma unroll
        for (int r = 0; r < 4; ++r) {
            const int s = srow0 + r;
            const float den = fmaxf(den_qkp[s] + den_qk[0][s] + den_qk[1][s], EPS_C);
            const float val = g * macc[r] + gl * lacc[r] / den;
            cb[(size_t)(s0 + s) * H_DIM + h * HD + e] = f2bf(val);
        }
    }
}

extern "C" void kernel_launch(void* const* d_in, const int* in_sizes, int n_in,
                              void* d_out, int out_size, void* d_ws, size_t ws_size,
                              hipStream_t stream) {
    const float* hidden   = (const float*)d_in[0];
    const float* w_q      = (const float*)d_in[1];
    const float* w_k      = (const float*)d_in[2];
    const float* w_v      = (const float*)d_in[3];
    const float* w_o      = (const float*)d_in[4];
    const float* gate     = (const float*)d_in[5];
    const float* memories = (const float*)d_in[6];
    const float* memnorms = (const float*)d_in[7];
    float* out = (float*)d_out;

    float* ws = (float*)d_ws;
    size_t off = 0;
    float* rel     = ws + off; off += (size_t)NMEM * NHEAD * S_LEN;
    float* relpart = ws + off; off += 256;
    float* cks     = ws + off; off += (size_t)NHEAD * NCHUNK * HD;
    float* cksc    = ws + off; off += (size_t)NHEAD * NCHUNK * HD;
    unsigned short* ckv_b  = (unsigned short*)(ws + off); off += (size_t)NHEAD * NCHUNK * HD * HD / 2;
    unsigned short* ckvT_b = (unsigned short*)(ws + off); off += (size_t)NHEAD * NCHUNK * HD * HD / 2;
    unsigned short* hb  = (unsigned short*)(ws + off); off += (size_t)S_LEN * H_DIM / 2;
    unsigned short* wb  = (unsigned short*)(ws + off); off += (size_t)3 * H_DIM * H_DIM / 2;
    unsigned short* wob = (unsigned short*)(ws + off); off += (size_t)H_DIM * H_DIM / 2;
    unsigned short* qb  = (unsigned short*)(ws + off); off += (size_t)S_LEN * H_DIM / 2;
    unsigned short* kb  = (unsigned short*)(ws + off); off += (size_t)S_LEN * H_DIM / 2;
    unsigned short* vb  = (unsigned short*)(ws + off); off += (size_t)S_LEN * H_DIM / 2;
    unsigned short* cb  = (unsigned short*)(ws + off); off += (size_t)S_LEN * H_DIM / 2;
    unsigned short* mbT = (unsigned short*)(ws + off); off += (size_t)NMEM * NHEAD * HD * HD / 2;

    // 1. conversions + memory transpose
    prep_kernel<<<3136, 256, 0, stream>>>(hidden, w_q, w_k, w_v, w_o, memories,
                                          hb, wb, wob, mbT);
    // 2. fused QKV projection (BM=128/BN=96/BK=64 dbuf, 512 blocks = 2/CU)
    gemm_mfma_kernel<1, 128, 96, 3072><<<512, 256, 0, stream>>>(
        hb, wb, nullptr, qb, kb, vb, H_DIM);
    // 3. per-chunk KV state + relevance (merged, 16x36 blocks)
    chunkkv_rel_kernel<<<dim3(NHEAD, 36), 256, 0, stream>>>(
        kb, vb, qb, memnorms, ckv_b, cksc, rel, relpart);
    // 4. exclusive prefix scan (upfront-load register scan, 128 blocks)
    prefix_kernel<<<dim3(NHEAD, 8), 256, 0, stream>>>(ckv_b, cksc, ckvT_b, cks);
    // 5. fused memory + local output (64-row tiles, 8 waves/block)
    fused_out_kernel<<<dim3(NHEAD, NCHUNK), 512, 0, stream>>>(
        qb, kb, vb, ckvT_b, cks, mbT, rel, relpart, gate, cb);
    // 6. output projection (BM=64/BN=64, 512 blocks = 2/CU)
    gemm_mfma_kernel<0, 64, 64, 1024><<<512, 256, 0, stream>>>(
        cb, wob, out, nullptr, nullptr, nullptr, H_DIM);
}